// Round 1
// baseline (1093.884 us; speedup 1.0000x reference)
//
#include <hip/hip_runtime.h>
#include <hip/hip_bf16.h>
#include <cmath>

#define N_NODES 50000
#define N_EDGES 800000
#define N_GRAPHS 1024
#define F_IN 35
#define H1 10
#define C1 35
#define HC1 350
#define C2 128

// ---------------- CSR build ----------------
__global__ void k_count(const int* __restrict__ dst, int* __restrict__ deg) {
    int e = blockIdx.x * blockDim.x + threadIdx.x;
    if (e < N_EDGES) atomicAdd(&deg[dst[e]], 1);
}

__global__ __launch_bounds__(1024) void k_scan(const int* __restrict__ deg,
                                               int* __restrict__ offs,
                                               int* __restrict__ cursor) {
    __shared__ int buf[1024];
    __shared__ int carry_s;
    const int tid = threadIdx.x;
    if (tid == 0) carry_s = 0;
    __syncthreads();
    for (int base = 0; base < N_NODES; base += 4096) {
        int i0 = base + tid * 4;
        int v0 = (i0 + 0 < N_NODES) ? deg[i0 + 0] : 0;
        int v1 = (i0 + 1 < N_NODES) ? deg[i0 + 1] : 0;
        int v2 = (i0 + 2 < N_NODES) ? deg[i0 + 2] : 0;
        int v3 = (i0 + 3 < N_NODES) ? deg[i0 + 3] : 0;
        int s = v0 + v1 + v2 + v3;
        buf[tid] = s;
        __syncthreads();
        for (int off = 1; off < 1024; off <<= 1) {
            int t = (tid >= off) ? buf[tid - off] : 0;
            __syncthreads();
            buf[tid] += t;
            __syncthreads();
        }
        int carry = carry_s;
        int p = carry + buf[tid] - s;  // exclusive prefix of this thread's group
        if (i0 + 0 < N_NODES) { offs[i0 + 0] = p; cursor[i0 + 0] = p; p += v0; }
        if (i0 + 1 < N_NODES) { offs[i0 + 1] = p; cursor[i0 + 1] = p; p += v1; }
        if (i0 + 2 < N_NODES) { offs[i0 + 2] = p; cursor[i0 + 2] = p; p += v2; }
        if (i0 + 3 < N_NODES) { offs[i0 + 3] = p; cursor[i0 + 3] = p; p += v3; }
        __syncthreads();
        if (tid == 1023) carry_s = carry + buf[1023];
        __syncthreads();
    }
    if (tid == 0) offs[N_NODES] = carry_s;
}

__global__ void k_fill(const int* __restrict__ src, const int* __restrict__ dst,
                       int* __restrict__ cursor, int* __restrict__ csr) {
    int e = blockIdx.x * blockDim.x + threadIdx.x;
    if (e < N_EDGES) {
        int p = atomicAdd(&cursor[dst[e]], 1);
        csr[p] = src[e];
    }
}

// ---------------- layer 1 GEMM: h1 = x @ W1 (pre-bias) ----------------
__global__ void k_gemm1(const float* __restrict__ x, const float* __restrict__ W1,
                        float* __restrict__ h1) {
    int idx = blockIdx.x * blockDim.x + threadIdx.x;
    if (idx >= N_NODES * HC1) return;
    int n = idx / HC1;
    int c = idx - n * HC1;
    const float* xr = x + n * F_IN;
    float acc = 0.f;
#pragma unroll
    for (int k = 0; k < F_IN; ++k) acc = fmaf(xr[k], W1[k * HC1 + c], acc);
    h1[idx] = acc;
}

// a_s1/a_d1 per (node, head)
__global__ void k_att1(const float* __restrict__ h1, const float* __restrict__ att_s,
                       const float* __restrict__ att_d, float* __restrict__ a_s,
                       float* __restrict__ a_d) {
    int idx = blockIdx.x * blockDim.x + threadIdx.x;
    if (idx >= N_NODES * H1) return;
    int n = idx / H1;
    int h = idx - n * H1;
    const float* hr = h1 + (long)n * HC1 + h * C1;
    const float* as = att_s + h * C1;
    const float* ad = att_d + h * C1;
    float s = 0.f, d = 0.f;
#pragma unroll
    for (int c = 0; c < C1; ++c) {
        float v = hr[c];
        s = fmaf(v, as[c], s);
        d = fmaf(v, ad[c], d);
    }
    a_s[idx] = s;
    a_d[idx] = d;
}

// ---------------- GAT aggregation: one wave (64 lanes) per dst node ----------------
// ACT: 0 = elu, 1 = relu
template <int H, int C, int ACT>
__global__ __launch_bounds__(64) void k_agg(const float* __restrict__ feat,
                                            const float* __restrict__ a_s,
                                            const float* __restrict__ a_d,
                                            const int* __restrict__ offs,
                                            const int* __restrict__ csr,
                                            const float* __restrict__ bias,
                                            float* __restrict__ out) {
    constexpr int HC = H * C;
    constexpr int CPL = (HC + 63) / 64;  // channels per lane
    __shared__ float al[64 * H];
    __shared__ int srcs[64];
    const int d = blockIdx.x;
    const int lane = threadIdx.x;
    const int o0 = offs[d];
    const int deg = offs[d + 1] - o0;
    const int total = deg + 1;  // + self loop (src = d) as edge index 'deg'

    float add[H];
#pragma unroll
    for (int h = 0; h < H; ++h) add[h] = a_d[d * H + h];

    // phase 1: per-lane online (max, denom) per head
    float lm[H], ld[H];
#pragma unroll
    for (int h = 0; h < H; ++h) { lm[h] = -INFINITY; ld[h] = 0.f; }
    for (int i = lane; i < total; i += 64) {
        int s = (i < deg) ? csr[o0 + i] : d;
#pragma unroll
        for (int h = 0; h < H; ++h) {
            float e = a_s[s * H + h] + add[h];
            e = (e > 0.f) ? e : 0.2f * e;  // leaky relu
            float mn = fmaxf(lm[h], e);
            ld[h] = ld[h] * __expf(lm[h] - mn) + __expf(e - mn);
            lm[h] = mn;
        }
    }
    // butterfly combine across the wave (guard -inf - -inf = nan)
#pragma unroll
    for (int off = 32; off > 0; off >>= 1) {
#pragma unroll
        for (int h = 0; h < H; ++h) {
            float m2 = __shfl_xor(lm[h], off);
            float d2 = __shfl_xor(ld[h], off);
            float mn = fmaxf(lm[h], m2);
            float e1 = (lm[h] == mn) ? 1.f : __expf(lm[h] - mn);
            float e2 = (m2 == mn) ? 1.f : __expf(m2 - mn);
            ld[h] = ld[h] * e1 + d2 * e2;
            lm[h] = mn;
        }
    }
    float rden[H];
#pragma unroll
    for (int h = 0; h < H; ++h) rden[h] = 1.f / ld[h];

    int myc[CPL], myh[CPL];
#pragma unroll
    for (int k = 0; k < CPL; ++k) {
        myc[k] = lane + 64 * k;
        myh[k] = myc[k] / C;
    }
    float acc[CPL];
#pragma unroll
    for (int k = 0; k < CPL; ++k) acc[k] = 0.f;

    // phase 2: chunked alpha -> LDS, channel-parallel gather-accumulate
    for (int base = 0; base < total; base += 64) {
        int i = base + lane;
        if (i < total) {
            int s = (i < deg) ? csr[o0 + i] : d;
            srcs[lane] = s;
#pragma unroll
            for (int h = 0; h < H; ++h) {
                float e = a_s[s * H + h] + add[h];
                e = (e > 0.f) ? e : 0.2f * e;
                al[lane * H + h] = __expf(e - lm[h]) * rden[h];
            }
        }
        __syncthreads();
        int cnt = min(64, total - base);
        for (int j = 0; j < cnt; ++j) {
            int s = srcs[j];
            const float* fr = feat + (long)s * HC;
#pragma unroll
            for (int k = 0; k < CPL; ++k) {
                if (myc[k] < HC) acc[k] = fmaf(al[j * H + myh[k]], fr[myc[k]], acc[k]);
            }
        }
        __syncthreads();
    }

#pragma unroll
    for (int k = 0; k < CPL; ++k) {
        if (myc[k] < HC) {
            float v = acc[k] + bias[myc[k]];
            if (ACT == 0) v = (v > 0.f) ? v : expm1f(v);   // elu
            else          v = fmaxf(v, 0.f);               // relu
            out[(long)d * HC + myc[k]] = v;
        }
    }
}

// ---------------- layer 2 GEMM: h2 = x2 @ W2 (+fused att dots) ----------------
__global__ __launch_bounds__(512) void k_gemm2(const float* __restrict__ x2,
                                               const float* __restrict__ W2,
                                               const float* __restrict__ att_s,
                                               const float* __restrict__ att_d,
                                               float* __restrict__ h2,
                                               float* __restrict__ a_s2,
                                               float* __restrict__ a_d2) {
    __shared__ float xs[4][HC1];
    __shared__ float red[8][2];
    const int tid = threadIdx.x;
    const int nb = blockIdx.x * 4;
    for (int idx = tid; idx < 4 * HC1; idx += 512) {
        int nn = idx / HC1;
        int cc = idx - nn * HC1;
        xs[nn][cc] = x2[(long)(nb + nn) * HC1 + cc];
    }
    __syncthreads();
    const int c = tid & 127;
    const int g = tid >> 7;
    const int n = nb + g;
    float acc = 0.f;
#pragma unroll 5
    for (int k = 0; k < HC1; ++k) acc = fmaf(xs[g][k], W2[k * C2 + c], acc);
    h2[(long)n * C2 + c] = acc;  // pre-bias, as reference
    float ps = acc * att_s[c];
    float pd = acc * att_d[c];
#pragma unroll
    for (int off = 32; off; off >>= 1) {
        ps += __shfl_down(ps, off);
        pd += __shfl_down(pd, off);
    }
    const int wave = tid >> 6;
    if ((tid & 63) == 0) { red[wave][0] = ps; red[wave][1] = pd; }
    __syncthreads();
    if (tid < 4) {
        a_s2[nb + tid] = red[2 * tid][0] + red[2 * tid + 1][0];
        a_d2[nb + tid] = red[2 * tid][1] + red[2 * tid + 1][1];
    }
}

// ---------------- pooling: run-length max + one atomic per (run, channel) ----------------
__global__ __launch_bounds__(128) void k_pool(const float* __restrict__ out2,
                                              const int* __restrict__ batch,
                                              float* __restrict__ pooled) {
    const int c = threadIdx.x;
    const int n0 = blockIdx.x * 256;
    const int n1 = (n0 + 256 < N_NODES) ? n0 + 256 : N_NODES;
    int curB = -1;
    float curM = 0.f;
    for (int n = n0; n < n1; ++n) {
        int b = batch[n];
        float v = out2[(long)n * C2 + c];
        if (b != curB) {
            if (curB >= 0) atomicMax((int*)&pooled[curB * C2 + c], __float_as_int(curM));
            curB = b;
            curM = v;
        } else {
            curM = fmaxf(curM, v);
        }
    }
    if (curB >= 0) atomicMax((int*)&pooled[curB * C2 + c], __float_as_int(curM));
}

// ---------------- dense head ----------------
__global__ __launch_bounds__(128) void k_head(const float* __restrict__ pooled,
                                              const float* __restrict__ Wg,
                                              const float* __restrict__ bg,
                                              const float* __restrict__ Wo,
                                              const float* __restrict__ bo,
                                              float* __restrict__ out) {
    __shared__ float p[C2];
    __shared__ float wsum[2];
    const int g = blockIdx.x;
    const int tid = threadIdx.x;
    p[tid] = pooled[g * C2 + tid];  // >= 0; empty graph stays 0 (matches ref where())
    __syncthreads();
    float acc = bg[tid];
#pragma unroll 8
    for (int k = 0; k < C2; ++k) acc = fmaf(p[k], Wg[k * C2 + tid], acc);
    float z = fmaxf(acc, 0.f);
    float prod = z * Wo[tid];
#pragma unroll
    for (int off = 32; off; off >>= 1) prod += __shfl_down(prod, off);
    if ((tid & 63) == 0) wsum[tid >> 6] = prod;
    __syncthreads();
    if (tid == 0) out[g] = wsum[0] + wsum[1] + bo[0];
}

extern "C" void kernel_launch(void* const* d_in, const int* in_sizes, int n_in,
                              void* d_out, int out_size, void* d_ws, size_t ws_size,
                              hipStream_t stream) {
    const float* x        = (const float*)d_in[0];
    const int*   ei       = (const int*)d_in[1];
    const int*   batch    = (const int*)d_in[2];
    const float* W1       = (const float*)d_in[3];
    const float* att_src1 = (const float*)d_in[4];
    const float* att_dst1 = (const float*)d_in[5];
    const float* b1       = (const float*)d_in[6];
    const float* W2       = (const float*)d_in[7];
    const float* att_src2 = (const float*)d_in[8];
    const float* att_dst2 = (const float*)d_in[9];
    const float* b2       = (const float*)d_in[10];
    const float* Wg       = (const float*)d_in[11];
    const float* bg       = (const float*)d_in[12];
    const float* Wo       = (const float*)d_in[13];
    const float* bo       = (const float*)d_in[14];
    const int* src = ei;
    const int* dst = ei + N_EDGES;

    char* ws = (char*)d_ws;
    size_t off = 0;
    auto alloc = [&](size_t bytes) -> char* {
        char* p = ws + off;
        off = (off + bytes + 255) & ~(size_t)255;
        return p;
    };
    int*   deg    = (int*)alloc((size_t)N_NODES * 4);
    int*   offs   = (int*)alloc((size_t)(N_NODES + 1) * 4);
    int*   cursor = (int*)alloc((size_t)N_NODES * 4);
    int*   csr    = (int*)alloc((size_t)N_EDGES * 4);
    float* a_s1   = (float*)alloc((size_t)N_NODES * H1 * 4);
    float* a_d1   = (float*)alloc((size_t)N_NODES * H1 * 4);
    float* a_s2   = (float*)alloc((size_t)N_NODES * 4);
    float* a_d2   = (float*)alloc((size_t)N_NODES * 4);
    float* pooled = (float*)alloc((size_t)N_GRAPHS * C2 * 4);
    float* h1     = (float*)alloc((size_t)N_NODES * HC1 * 4);
    float* x2     = (float*)alloc((size_t)N_NODES * HC1 * 4);
    float* h2     = (float*)alloc((size_t)N_NODES * C2 * 4);
    float* out2   = h1;  // h1 dead after k_agg1 -> reuse for layer-2 output

    hipMemsetAsync(deg, 0, (size_t)N_NODES * 4, stream);
    hipMemsetAsync(pooled, 0, (size_t)N_GRAPHS * C2 * 4, stream);

    k_count<<<(N_EDGES + 255) / 256, 256, 0, stream>>>(dst, deg);
    k_scan<<<1, 1024, 0, stream>>>(deg, offs, cursor);
    k_fill<<<(N_EDGES + 255) / 256, 256, 0, stream>>>(src, dst, cursor, csr);

    k_gemm1<<<(N_NODES * HC1 + 255) / 256, 256, 0, stream>>>(x, W1, h1);
    k_att1<<<(N_NODES * H1 + 255) / 256, 256, 0, stream>>>(h1, att_src1, att_dst1, a_s1, a_d1);
    k_agg<H1, C1, 0><<<N_NODES, 64, 0, stream>>>(h1, a_s1, a_d1, offs, csr, b1, x2);

    k_gemm2<<<N_NODES / 4, 512, 0, stream>>>(x2, W2, att_src2, att_dst2, h2, a_s2, a_d2);
    k_agg<1, C2, 1><<<N_NODES, 64, 0, stream>>>(h2, a_s2, a_d2, offs, csr, b2, out2);

    k_pool<<<(N_NODES + 255) / 256, 128, 0, stream>>>(out2, batch, pooled);
    k_head<<<N_GRAPHS, 128, 0, stream>>>(pooled, Wg, bg, Wo, bo, (float*)d_out);
}

// Round 2
// 568.898 us; speedup vs baseline: 1.9228x; 1.9228x over previous
//
#include <hip/hip_runtime.h>
#include <hip/hip_bf16.h>
#include <cmath>

#define N_NODES 50000
#define N_EDGES 800000
#define N_GRAPHS 1024
#define F_IN 35
#define H1 10
#define C1 35
#define HC1 350
#define C2 128

typedef unsigned int uint32;
typedef __attribute__((ext_vector_type(8))) short short8;
typedef __attribute__((ext_vector_type(4))) float f32x4;

static __device__ __forceinline__ float bflo(uint32 u) { return __uint_as_float(u << 16); }
static __device__ __forceinline__ float bfhi(uint32 u) { return __uint_as_float(u & 0xffff0000u); }
static __device__ __forceinline__ unsigned short bfbits(float f) {
    return __builtin_bit_cast(unsigned short, __float2bfloat16(f));
}
static __device__ __forceinline__ uint32 packbf(float a, float b) {
    return ((uint32)bfbits(b) << 16) | (uint32)bfbits(a);
}

// ---------------- CSR build ----------------
__global__ void k_count(const int* __restrict__ dst, int* __restrict__ deg) {
    int e = blockIdx.x * blockDim.x + threadIdx.x;
    if (e < N_EDGES) atomicAdd(&deg[dst[e]], 1);
}

__global__ __launch_bounds__(1024) void k_scan(const int* __restrict__ deg,
                                               int* __restrict__ offs,
                                               int* __restrict__ cursor) {
    __shared__ int buf[1024];
    __shared__ int carry_s;
    const int tid = threadIdx.x;
    if (tid == 0) carry_s = 0;
    __syncthreads();
    for (int base = 0; base < N_NODES; base += 4096) {
        int i0 = base + tid * 4;
        int v0 = (i0 + 0 < N_NODES) ? deg[i0 + 0] : 0;
        int v1 = (i0 + 1 < N_NODES) ? deg[i0 + 1] : 0;
        int v2 = (i0 + 2 < N_NODES) ? deg[i0 + 2] : 0;
        int v3 = (i0 + 3 < N_NODES) ? deg[i0 + 3] : 0;
        int s = v0 + v1 + v2 + v3;
        buf[tid] = s;
        __syncthreads();
        for (int off = 1; off < 1024; off <<= 1) {
            int t = (tid >= off) ? buf[tid - off] : 0;
            __syncthreads();
            buf[tid] += t;
            __syncthreads();
        }
        int carry = carry_s;
        int p = carry + buf[tid] - s;
        if (i0 + 0 < N_NODES) { offs[i0 + 0] = p; cursor[i0 + 0] = p; p += v0; }
        if (i0 + 1 < N_NODES) { offs[i0 + 1] = p; cursor[i0 + 1] = p; p += v1; }
        if (i0 + 2 < N_NODES) { offs[i0 + 2] = p; cursor[i0 + 2] = p; p += v2; }
        if (i0 + 3 < N_NODES) { offs[i0 + 3] = p; cursor[i0 + 3] = p; p += v3; }
        __syncthreads();
        if (tid == 1023) carry_s = carry + buf[1023];
        __syncthreads();
    }
    if (tid == 0) offs[N_NODES] = carry_s;
}

__global__ void k_fill(const int* __restrict__ src, const int* __restrict__ dst,
                       int* __restrict__ cursor, int* __restrict__ csr) {
    int e = blockIdx.x * blockDim.x + threadIdx.x;
    if (e < N_EDGES) {
        int p = atomicAdd(&cursor[dst[e]], 1);
        csr[p] = src[e];
    }
}

// ---------------- layer 1 GEMM: h1b(bf16) = x @ W1, channel pairs ----------------
__global__ void k_gemm1(const float* __restrict__ x, const float* __restrict__ W1,
                        uint32* __restrict__ h1b) {
    int idx = blockIdx.x * blockDim.x + threadIdx.x;
    if (idx >= N_NODES * 175) return;
    int n = idx / 175;
    int cp = idx - n * 175;
    const float* xr = x + n * F_IN;
    const float* w = W1 + 2 * cp;
    float a0 = 0.f, a1 = 0.f;
#pragma unroll
    for (int k = 0; k < F_IN; ++k) {
        float xv = xr[k];
        a0 = fmaf(xv, w[k * HC1], a0);
        a1 = fmaf(xv, w[k * HC1 + 1], a1);
    }
    h1b[idx] = packbf(a0, a1);
}

// a_s1/a_d1 per (node, head) from bf16 h1
__global__ void k_att1(const unsigned short* __restrict__ h1b,
                       const float* __restrict__ att_s, const float* __restrict__ att_d,
                       float* __restrict__ a_s, float* __restrict__ a_d) {
    int idx = blockIdx.x * blockDim.x + threadIdx.x;
    if (idx >= N_NODES * H1) return;
    int n = idx / H1;
    int h = idx - n * H1;
    const unsigned short* hr = h1b + (long)n * HC1 + h * C1;
    const float* as = att_s + h * C1;
    const float* ad = att_d + h * C1;
    float s = 0.f, d = 0.f;
#pragma unroll
    for (int c = 0; c < C1; ++c) {
        float v = __uint_as_float((uint32)hr[c] << 16);
        s = fmaf(v, as[c], s);
        d = fmaf(v, ad[c], d);
    }
    a_s[idx] = s;
    a_d[idx] = d;
}

// ---------------- layer-1 aggregation: one wave per dst node, bf16 gather ----------------
__global__ __launch_bounds__(64) void k_agg1(const uint32* __restrict__ feat,  // [N][175]
                                             const float* __restrict__ a_s,   // [N][10]
                                             const float* __restrict__ a_d,
                                             const int* __restrict__ offs,
                                             const int* __restrict__ csr,
                                             const float* __restrict__ bias,  // [350]
                                             uint32* __restrict__ x2p) {      // [N][176]
    __shared__ float al[640];
    __shared__ int srcs[64];
    const int d = blockIdx.x, lane = threadIdx.x;
    const int o0 = offs[d];
    const int deg = offs[d + 1] - o0;
    const int total = deg + 1;  // self-loop as edge 'deg'

    float add[10];
#pragma unroll
    for (int h = 0; h < 10; ++h) add[h] = a_d[d * 10 + h];

    float lm[10], ld[10];
#pragma unroll
    for (int h = 0; h < 10; ++h) { lm[h] = -INFINITY; ld[h] = 0.f; }
    for (int i = lane; i < total; i += 64) {
        int s = (i < deg) ? csr[o0 + i] : d;
#pragma unroll
        for (int h = 0; h < 10; ++h) {
            float e = a_s[s * 10 + h] + add[h];
            e = (e > 0.f) ? e : 0.2f * e;
            float mn = fmaxf(lm[h], e);
            ld[h] = ld[h] * __expf(lm[h] - mn) + __expf(e - mn);
            lm[h] = mn;
        }
    }
#pragma unroll
    for (int off = 32; off > 0; off >>= 1) {
#pragma unroll
        for (int h = 0; h < 10; ++h) {
            float m2 = __shfl_xor(lm[h], off);
            float d2 = __shfl_xor(ld[h], off);
            float mn = fmaxf(lm[h], m2);
            float e1 = (lm[h] == mn) ? 1.f : __expf(lm[h] - mn);
            float e2 = (m2 == mn) ? 1.f : __expf(m2 - mn);
            ld[h] = ld[h] * e1 + d2 * e2;
            lm[h] = mn;
        }
    }
    float rden[10];
#pragma unroll
    for (int h = 0; h < 10; ++h) rden[h] = 1.f / ld[h];

    const int p0 = lane, p1 = lane + 64, p2 = lane + 128;
    const bool has2 = (p2 < 175);
    const int hA0 = (2 * p0) / 35, hB0 = (2 * p0 + 1) / 35;
    const int hA1 = (2 * p1) / 35, hB1 = (2 * p1 + 1) / 35;
    const int hA2 = has2 ? (2 * p2) / 35 : 0, hB2 = has2 ? (2 * p2 + 1) / 35 : 0;

    float ac0 = 0, ac1 = 0, ac2 = 0, ac3 = 0, ac4 = 0, ac5 = 0;

    for (int base = 0; base < total; base += 64) {
        int i = base + lane;
        if (i < total) {
            int s = (i < deg) ? csr[o0 + i] : d;
            srcs[lane] = s;
#pragma unroll
            for (int h = 0; h < 10; ++h) {
                float e = a_s[s * 10 + h] + add[h];
                e = (e > 0.f) ? e : 0.2f * e;
                al[lane * 10 + h] = __expf(e - lm[h]) * rden[h];
            }
        }
        __syncthreads();
        int cnt = min(64, total - base);
        int s0 = srcs[0];
        uint32 u0 = feat[s0 * 175 + p0];
        uint32 u1 = feat[s0 * 175 + p1];
        uint32 u2 = has2 ? feat[s0 * 175 + p2] : 0u;
        for (int j = 0; j < cnt; ++j) {
            uint32 v0 = u0, v1 = u1, v2 = u2;
            if (j + 1 < cnt) {  // software pipeline: issue next edge's gathers
                int sn = srcs[j + 1];
                u0 = feat[sn * 175 + p0];
                u1 = feat[sn * 175 + p1];
                u2 = has2 ? feat[sn * 175 + p2] : 0u;
            }
            const float* alj = &al[j * 10];
            ac0 = fmaf(alj[hA0], bflo(v0), ac0);
            ac1 = fmaf(alj[hB0], bfhi(v0), ac1);
            ac2 = fmaf(alj[hA1], bflo(v1), ac2);
            ac3 = fmaf(alj[hB1], bfhi(v1), ac3);
            if (has2) {
                ac4 = fmaf(alj[hA2], bflo(v2), ac4);
                ac5 = fmaf(alj[hB2], bfhi(v2), ac5);
            }
        }
        __syncthreads();
    }
    // epilogue: bias + elu, pack to bf16, pad K to 352 for MFMA
    {
        float v0 = ac0 + bias[2 * p0], v1 = ac1 + bias[2 * p0 + 1];
        v0 = (v0 > 0.f) ? v0 : expm1f(v0);
        v1 = (v1 > 0.f) ? v1 : expm1f(v1);
        x2p[(long)d * 176 + p0] = packbf(v0, v1);
        float w0 = ac2 + bias[2 * p1], w1 = ac3 + bias[2 * p1 + 1];
        w0 = (w0 > 0.f) ? w0 : expm1f(w0);
        w1 = (w1 > 0.f) ? w1 : expm1f(w1);
        x2p[(long)d * 176 + p1] = packbf(w0, w1);
        if (has2) {
            float y0 = ac4 + bias[2 * p2], y1 = ac5 + bias[2 * p2 + 1];
            y0 = (y0 > 0.f) ? y0 : expm1f(y0);
            y1 = (y1 > 0.f) ? y1 : expm1f(y1);
            x2p[(long)d * 176 + p2] = packbf(y0, y1);
        } else if (p2 == 175) {
            x2p[(long)d * 176 + 175] = 0u;  // zero pad channels 350,351
        }
    }
}

// ---------------- W2 -> bf16 MFMA B-fragment layout [11 ksteps][8 ntiles][64 lanes][8 k] ----------------
__global__ void k_prep_w2(const float* __restrict__ W2, uint32* __restrict__ W2f) {
    int idx = blockIdx.x * blockDim.x + threadIdx.x;
    if (idx >= 11 * 8 * 64) return;
    int lane = idx & 63;
    int t = (idx >> 6) & 7;
    int kk = idx >> 9;
    int c = t * 16 + (lane & 15);
    int k0 = kk * 32 + (lane >> 4) * 8;
    uint32 o[4];
#pragma unroll
    for (int jj = 0; jj < 4; ++jj) {
        int ka = k0 + 2 * jj, kb = ka + 1;
        float va = (ka < HC1) ? W2[ka * C2 + c] : 0.f;
        float vb = (kb < HC1) ? W2[kb * C2 + c] : 0.f;
        o[jj] = packbf(va, vb);
    }
    uint32* dst = W2f + idx * 4;
    dst[0] = o[0]; dst[1] = o[1]; dst[2] = o[2]; dst[3] = o[3];
}

// ---------------- layer 2 GEMM via MFMA: h2b(bf16) = x2p @ W2, fused att dots ----------------
__global__ __launch_bounds__(256) void k_gemm2(const short* __restrict__ x2p,       // [N][352] bf16
                                               const short8* __restrict__ W2f,      // frag layout
                                               const float* __restrict__ attS,      // [128]
                                               const float* __restrict__ attD,
                                               unsigned short* __restrict__ h2b,    // [N][128] bf16
                                               float* __restrict__ a_s2, float* __restrict__ a_d2) {
    const int lane = threadIdx.x & 63;
    const int wid = threadIdx.x >> 6;
    const int mtile = blockIdx.x * 4 + wid;
    if (mtile >= N_NODES / 16) return;
    const int c_lo = lane & 15, grp = lane >> 4;
    const int m0 = mtile * 16;
    const short* aptr = x2p + (long)(m0 + c_lo) * 352 + grp * 8;  // A row = lane&15

    f32x4 acc[8];
#pragma unroll
    for (int t = 0; t < 8; ++t) acc[t] = (f32x4){0.f, 0.f, 0.f, 0.f};

#pragma unroll
    for (int kk = 0; kk < 11; ++kk) {
        short8 a = *reinterpret_cast<const short8*>(aptr + kk * 32);
#pragma unroll
        for (int t = 0; t < 8; ++t) {
            short8 b = W2f[(kk * 8 + t) * 64 + lane];
            acc[t] = __builtin_amdgcn_mfma_f32_16x16x32_bf16(a, b, acc[t], 0, 0, 0);
        }
    }

    float attSv[8], attDv[8];
#pragma unroll
    for (int t = 0; t < 8; ++t) {
        attSv[t] = attS[t * 16 + c_lo];
        attDv[t] = attD[t * 16 + c_lo];
    }
    float ps[4] = {0, 0, 0, 0}, pd[4] = {0, 0, 0, 0};
#pragma unroll
    for (int t = 0; t < 8; ++t)
#pragma unroll
        for (int r = 0; r < 4; ++r) {
            ps[r] = fmaf(acc[t][r], attSv[t], ps[r]);
            pd[r] = fmaf(acc[t][r], attDv[t], pd[r]);
        }
    // store h2 bf16: D mapping col=lane&15(channel), row=grp*4+r(node)
#pragma unroll
    for (int r = 0; r < 4; ++r) {
        int node = m0 + grp * 4 + r;
#pragma unroll
        for (int t = 0; t < 8; ++t) h2b[(long)node * C2 + t * 16 + c_lo] = bfbits(acc[t][r]);
    }
#pragma unroll
    for (int r = 0; r < 4; ++r) {
        float s = ps[r], dd = pd[r];
#pragma unroll
        for (int off = 1; off < 16; off <<= 1) {
            s += __shfl_xor(s, off);
            dd += __shfl_xor(dd, off);
        }
        if (c_lo == 0) {
            int node = m0 + grp * 4 + r;
            a_s2[node] = s;
            a_d2[node] = dd;
        }
    }
}

// ---------------- layer-2 aggregation + fused bias/relu/max-pool ----------------
__global__ __launch_bounds__(64) void k_agg2(const uint32* __restrict__ feat,  // h2b [N][64] dwords
                                             const float* __restrict__ a_s,   // [N]
                                             const float* __restrict__ a_d,
                                             const int* __restrict__ offs,
                                             const int* __restrict__ csr,
                                             const float* __restrict__ b2,    // [128]
                                             const int* __restrict__ batch,
                                             float* __restrict__ pooled) {    // [G][128]
    __shared__ float al[64];
    __shared__ int srcs[64];
    const int d = blockIdx.x, lane = threadIdx.x;
    const int o0 = offs[d];
    const int deg = offs[d + 1] - o0;
    const int total = deg + 1;
    const float add = a_d[d];

    float lm = -INFINITY, ldn = 0.f;
    for (int i = lane; i < total; i += 64) {
        int s = (i < deg) ? csr[o0 + i] : d;
        float e = a_s[s] + add;
        e = (e > 0.f) ? e : 0.2f * e;
        float mn = fmaxf(lm, e);
        ldn = ldn * __expf(lm - mn) + __expf(e - mn);
        lm = mn;
    }
#pragma unroll
    for (int off = 32; off > 0; off >>= 1) {
        float m2 = __shfl_xor(lm, off);
        float d2 = __shfl_xor(ldn, off);
        float mn = fmaxf(lm, m2);
        float e1 = (lm == mn) ? 1.f : __expf(lm - mn);
        float e2 = (m2 == mn) ? 1.f : __expf(m2 - mn);
        ldn = ldn * e1 + d2 * e2;
        lm = mn;
    }
    float rden = 1.f / ldn;

    float ac0 = 0.f, ac1 = 0.f;
    for (int base = 0; base < total; base += 64) {
        int i = base + lane;
        if (i < total) {
            int s = (i < deg) ? csr[o0 + i] : d;
            srcs[lane] = s;
            float e = a_s[s] + add;
            e = (e > 0.f) ? e : 0.2f * e;
            al[lane] = __expf(e - lm) * rden;
        }
        __syncthreads();
        int cnt = min(64, total - base);
        uint32 u = feat[srcs[0] * 64 + lane];
        for (int j = 0; j < cnt; ++j) {
            uint32 v = u;
            if (j + 1 < cnt) u = feat[srcs[j + 1] * 64 + lane];
            float a = al[j];
            ac0 = fmaf(a, bflo(v), ac0);
            ac1 = fmaf(a, bfhi(v), ac1);
        }
        __syncthreads();
    }
    int b = batch[d];
    float v0 = fmaxf(ac0 + b2[2 * lane], 0.f);
    float v1 = fmaxf(ac1 + b2[2 * lane + 1], 0.f);
    // relu>=0 and pooled zero-init: int atomicMax on float bits is order-preserving
    atomicMax((int*)&pooled[b * C2 + 2 * lane], __float_as_int(v0));
    atomicMax((int*)&pooled[b * C2 + 2 * lane + 1], __float_as_int(v1));
}

// ---------------- dense head ----------------
__global__ __launch_bounds__(128) void k_head(const float* __restrict__ pooled,
                                              const float* __restrict__ Wg,
                                              const float* __restrict__ bg,
                                              const float* __restrict__ Wo,
                                              const float* __restrict__ bo,
                                              float* __restrict__ out) {
    __shared__ float p[C2];
    __shared__ float wsum[2];
    const int g = blockIdx.x;
    const int tid = threadIdx.x;
    p[tid] = pooled[g * C2 + tid];
    __syncthreads();
    float acc = bg[tid];
#pragma unroll 8
    for (int k = 0; k < C2; ++k) acc = fmaf(p[k], Wg[k * C2 + tid], acc);
    float z = fmaxf(acc, 0.f);
    float prod = z * Wo[tid];
#pragma unroll
    for (int off = 32; off; off >>= 1) prod += __shfl_down(prod, off);
    if ((tid & 63) == 0) wsum[tid >> 6] = prod;
    __syncthreads();
    if (tid == 0) out[g] = wsum[0] + wsum[1] + bo[0];
}

extern "C" void kernel_launch(void* const* d_in, const int* in_sizes, int n_in,
                              void* d_out, int out_size, void* d_ws, size_t ws_size,
                              hipStream_t stream) {
    const float* x        = (const float*)d_in[0];
    const int*   ei       = (const int*)d_in[1];
    const int*   batch    = (const int*)d_in[2];
    const float* W1       = (const float*)d_in[3];
    const float* att_src1 = (const float*)d_in[4];
    const float* att_dst1 = (const float*)d_in[5];
    const float* b1       = (const float*)d_in[6];
    const float* W2       = (const float*)d_in[7];
    const float* att_src2 = (const float*)d_in[8];
    const float* att_dst2 = (const float*)d_in[9];
    const float* b2       = (const float*)d_in[10];
    const float* Wg       = (const float*)d_in[11];
    const float* bg       = (const float*)d_in[12];
    const float* Wo       = (const float*)d_in[13];
    const float* bo       = (const float*)d_in[14];
    const int* src = ei;
    const int* dst = ei + N_EDGES;

    char* ws = (char*)d_ws;
    size_t off = 0;
    auto alloc = [&](size_t bytes) -> char* {
        char* p = ws + off;
        off = (off + bytes + 255) & ~(size_t)255;
        return p;
    };
    int*    deg    = (int*)alloc((size_t)N_NODES * 4);
    int*    offs   = (int*)alloc((size_t)(N_NODES + 1) * 4);
    int*    cursor = (int*)alloc((size_t)N_NODES * 4);
    int*    csr    = (int*)alloc((size_t)N_EDGES * 4);
    float*  a_s1   = (float*)alloc((size_t)N_NODES * H1 * 4);
    float*  a_d1   = (float*)alloc((size_t)N_NODES * H1 * 4);
    float*  a_s2   = (float*)alloc((size_t)N_NODES * 4);
    float*  a_d2   = (float*)alloc((size_t)N_NODES * 4);
    float*  pooled = (float*)alloc((size_t)N_GRAPHS * C2 * 4);
    uint32* h1b    = (uint32*)alloc((size_t)N_NODES * 175 * 4);   // [N][350] bf16
    uint32* x2p    = (uint32*)alloc((size_t)N_NODES * 176 * 4);   // [N][352] bf16, K-padded
    unsigned short* h2b = (unsigned short*)alloc((size_t)N_NODES * C2 * 2);
    uint32* W2f    = (uint32*)alloc((size_t)11 * 8 * 64 * 16);

    hipMemsetAsync(deg, 0, (size_t)N_NODES * 4, stream);
    hipMemsetAsync(pooled, 0, (size_t)N_GRAPHS * C2 * 4, stream);

    k_count<<<(N_EDGES + 255) / 256, 256, 0, stream>>>(dst, deg);
    k_scan<<<1, 1024, 0, stream>>>(deg, offs, cursor);
    k_fill<<<(N_EDGES + 255) / 256, 256, 0, stream>>>(src, dst, cursor, csr);

    k_gemm1<<<(N_NODES * 175 + 255) / 256, 256, 0, stream>>>(x, W1, h1b);
    k_att1<<<(N_NODES * H1 + 255) / 256, 256, 0, stream>>>((const unsigned short*)h1b,
                                                           att_src1, att_dst1, a_s1, a_d1);
    k_prep_w2<<<(11 * 8 * 64 + 255) / 256, 256, 0, stream>>>(W2, W2f);

    k_agg1<<<N_NODES, 64, 0, stream>>>(h1b, a_s1, a_d1, offs, csr, b1, x2p);

    k_gemm2<<<(N_NODES / 16 + 3) / 4, 256, 0, stream>>>((const short*)x2p, (const short8*)W2f,
                                                        att_src2, att_dst2, h2b, a_s2, a_d2);

    k_agg2<<<N_NODES, 64, 0, stream>>>((const uint32*)h2b, a_s2, a_d2, offs, csr, b2, batch, pooled);

    k_head<<<N_GRAPHS, 128, 0, stream>>>(pooled, Wg, bg, Wo, bo, (float*)d_out);
}

// Round 3
// 504.775 us; speedup vs baseline: 2.1671x; 1.1270x over previous
//
#include <hip/hip_runtime.h>
#include <hip/hip_bf16.h>
#include <cmath>

#define N_NODES 50000
#define N_EDGES 800000
#define N_GRAPHS 1024
#define F_IN 35
#define H1 10
#define C1 35
#define HC1 350
#define C2 128

typedef unsigned int uint32;
typedef __attribute__((ext_vector_type(8))) short short8;
typedef __attribute__((ext_vector_type(4))) float f32x4;

static __device__ __forceinline__ float bflo(uint32 u) { return __uint_as_float(u << 16); }
static __device__ __forceinline__ float bfhi(uint32 u) { return __uint_as_float(u & 0xffff0000u); }
static __device__ __forceinline__ unsigned short bfbits(float f) {
    return __builtin_bit_cast(unsigned short, __float2bfloat16(f));
}
static __device__ __forceinline__ uint32 packbf(float a, float b) {
    return ((uint32)bfbits(b) << 16) | (uint32)bfbits(a);
}
static __device__ __forceinline__ float lrelu(float e) { return (e > 0.f) ? e : 0.2f * e; }

// ---------------- CSR build ----------------
__global__ void k_count(const int* __restrict__ dst, int* __restrict__ deg) {
    int e = blockIdx.x * blockDim.x + threadIdx.x;
    if (e < N_EDGES) atomicAdd(&deg[dst[e]], 1);
}

__global__ __launch_bounds__(1024) void k_scan(const int* __restrict__ deg,
                                               int* __restrict__ offs,
                                               int* __restrict__ cursor) {
    __shared__ int buf[1024];
    __shared__ int carry_s;
    const int tid = threadIdx.x;
    if (tid == 0) carry_s = 0;
    __syncthreads();
    for (int base = 0; base < N_NODES; base += 4096) {
        int i0 = base + tid * 4;
        int v0 = (i0 + 0 < N_NODES) ? deg[i0 + 0] : 0;
        int v1 = (i0 + 1 < N_NODES) ? deg[i0 + 1] : 0;
        int v2 = (i0 + 2 < N_NODES) ? deg[i0 + 2] : 0;
        int v3 = (i0 + 3 < N_NODES) ? deg[i0 + 3] : 0;
        int s = v0 + v1 + v2 + v3;
        buf[tid] = s;
        __syncthreads();
        for (int off = 1; off < 1024; off <<= 1) {
            int t = (tid >= off) ? buf[tid - off] : 0;
            __syncthreads();
            buf[tid] += t;
            __syncthreads();
        }
        int carry = carry_s;
        int p = carry + buf[tid] - s;
        if (i0 + 0 < N_NODES) { offs[i0 + 0] = p; cursor[i0 + 0] = p; p += v0; }
        if (i0 + 1 < N_NODES) { offs[i0 + 1] = p; cursor[i0 + 1] = p; p += v1; }
        if (i0 + 2 < N_NODES) { offs[i0 + 2] = p; cursor[i0 + 2] = p; p += v2; }
        if (i0 + 3 < N_NODES) { offs[i0 + 3] = p; cursor[i0 + 3] = p; p += v3; }
        __syncthreads();
        if (tid == 1023) carry_s = carry + buf[1023];
        __syncthreads();
    }
    if (tid == 0) offs[N_NODES] = carry_s;
}

__global__ void k_fill(const int* __restrict__ src, const int* __restrict__ dst,
                       int* __restrict__ cursor, int* __restrict__ csr) {
    int e = blockIdx.x * blockDim.x + threadIdx.x;
    if (e < N_EDGES) {
        int p = atomicAdd(&cursor[dst[e]], 1);
        csr[p] = src[e];
    }
}

// ---------------- x (fp32 [N][35]) -> bf16 [N][64] zero-padded ----------------
__global__ void k_xbf(const float* __restrict__ x, uint32* __restrict__ xbf) {
    int idx = blockIdx.x * blockDim.x + threadIdx.x;
    if (idx >= N_NODES * 8) return;
    int n = idx >> 3, t = idx & 7;
    uint32 o[4];
#pragma unroll
    for (int p = 0; p < 4; ++p) {
        int k0 = t * 8 + 2 * p;
        float a = (k0 < F_IN) ? x[(size_t)n * F_IN + k0] : 0.f;
        float b = (k0 + 1 < F_IN) ? x[(size_t)n * F_IN + k0 + 1] : 0.f;
        o[p] = packbf(a, b);
    }
    uint32* d = xbf + (size_t)n * 32 + t * 4;
    d[0] = o[0]; d[1] = o[1]; d[2] = o[2]; d[3] = o[3];
}

// ---------------- W1 (+ folded att vectors) -> B-fragment layout ----------------
// B cols: 0..349 = W1, 350/351 = 0, 352..361 = vs (a_src per head), 368..377 = vd, else 0
// layout: [2 ksteps][24 ntiles][64 lanes][8 k] bf16
__global__ void k_prep_w1(const float* __restrict__ W1, const float* __restrict__ attS,
                          const float* __restrict__ attD, uint32* __restrict__ W1f) {
    int idx = blockIdx.x * blockDim.x + threadIdx.x;
    if (idx >= 2 * 24 * 64) return;
    int lane = idx & 63;
    int t = (idx >> 6) % 24;
    int kk = idx / (24 * 64);
    int c = t * 16 + (lane & 15);
    int k0 = kk * 32 + (lane >> 4) * 8;
    uint32 o[4];
#pragma unroll
    for (int jj = 0; jj < 4; ++jj) {
        float v[2];
#pragma unroll
        for (int half = 0; half < 2; ++half) {
            int k = k0 + 2 * jj + half;
            float val = 0.f;
            if (k < F_IN) {
                if (c < HC1) {
                    val = W1[k * HC1 + c];
                } else if (c >= 352 && c < 362) {
                    int h = c - 352;
                    float s = 0.f;
                    for (int cc = 0; cc < C1; ++cc)
                        s = fmaf(W1[k * HC1 + h * C1 + cc], attS[h * C1 + cc], s);
                    val = s;
                } else if (c >= 368 && c < 378) {
                    int h = c - 368;
                    float s = 0.f;
                    for (int cc = 0; cc < C1; ++cc)
                        s = fmaf(W1[k * HC1 + h * C1 + cc], attD[h * C1 + cc], s);
                    val = s;
                }
            }
            v[half] = val;
        }
        o[jj] = packbf(v[0], v[1]);
    }
    uint32* d = W1f + (size_t)idx * 4;
    d[0] = o[0]; d[1] = o[1]; d[2] = o[2]; d[3] = o[3];
}

// ---------------- layer-1 GEMM via MFMA: h1b = x@W1 (bf16), a_s1/a_d1 fused ----------------
__global__ __launch_bounds__(256) void k_gemm1(const short* __restrict__ xbf,      // [N][64]
                                               const short8* __restrict__ W1f,
                                               unsigned short* __restrict__ h1b,   // [N][352]
                                               float* __restrict__ a_s1,           // [N][10]
                                               float* __restrict__ a_d1) {
    const int lane = threadIdx.x & 63;
    const int wid = threadIdx.x >> 6;
    const int mtile = blockIdx.x * 4 + wid;
    if (mtile >= N_NODES / 16) return;
    const int c_lo = lane & 15, grp = lane >> 4;
    const int m0 = mtile * 16;
    const short* aptr = xbf + (size_t)(m0 + c_lo) * 64 + grp * 8;

    f32x4 acc[24];
#pragma unroll
    for (int t = 0; t < 24; ++t) acc[t] = (f32x4){0.f, 0.f, 0.f, 0.f};
#pragma unroll
    for (int kk = 0; kk < 2; ++kk) {
        short8 a = *reinterpret_cast<const short8*>(aptr + kk * 32);
#pragma unroll
        for (int t = 0; t < 24; ++t) {
            short8 b = W1f[(kk * 24 + t) * 64 + lane];
            acc[t] = __builtin_amdgcn_mfma_f32_16x16x32_bf16(a, b, acc[t], 0, 0, 0);
        }
    }
#pragma unroll
    for (int r = 0; r < 4; ++r) {
        int node = m0 + grp * 4 + r;
#pragma unroll
        for (int t = 0; t < 22; ++t)
            h1b[(size_t)node * 352 + t * 16 + c_lo] = bfbits(acc[t][r]);
        if (c_lo < 10) {
            a_s1[node * 10 + c_lo] = acc[22][r];
            a_d1[node * 10 + c_lo] = acc[23][r];
        }
    }
}

// ---------------- layer-1 aggregation: 4 nodes/block, 1 wave each ----------------
__global__ __launch_bounds__(256) void k_agg1(const uint4* __restrict__ feat4,  // h1b [N][44] x16B
                                              const float* __restrict__ a_s,   // [N][10]
                                              const float* __restrict__ a_d,
                                              const int* __restrict__ offs,
                                              const int* __restrict__ csr,
                                              const float* __restrict__ bias,  // [350]
                                              uint4* __restrict__ x2p4) {      // [N][44] x16B
    __shared__ float al[4][10][68];
    __shared__ float rdn[4][10];
    __shared__ int totmax[4];
    const int lane = threadIdx.x & 63;
    const int wid = threadIdx.x >> 6;
    const int d = blockIdx.x * 4 + wid;
    const int o0 = offs[d];
    const int deg = offs[d + 1] - o0;
    const int total = deg + 1;  // self-loop as edge 'deg'
    if (lane == 0) totmax[wid] = total;
    __syncthreads();
    const int tmx = max(max(totmax[0], totmax[1]), max(totmax[2], totmax[3]));
    const int rounds = (tmx + 63) >> 6;

    float add[10];
    {
        const float2* ap = (const float2*)(a_d + (size_t)d * 10);
#pragma unroll
        for (int p = 0; p < 5; ++p) { float2 v = ap[p]; add[2 * p] = v.x; add[2 * p + 1] = v.y; }
    }
    // per-lane channel geometry: lane L covers channels 8L..8L+7 (L<44)
    const int L = lane;
    const bool haveCh = (L < 44);
    const int hLo = (8 * L) / 35;
    const int hHi = min((8 * L + 7) / 35, 9);
    const int bnd = 35 * hHi;  // first channel of hHi (if hHi==hLo this is <= 8L -> always "hi"==same)

    float acc[8];
#pragma unroll
    for (int q = 0; q < 8; ++q) acc[q] = 0.f;
    float den[10];
#pragma unroll
    for (int h = 0; h < 10; ++h) den[h] = 0.f;

    for (int rb = 0; rb < rounds; ++rb) {
        const int base = rb << 6;
        const int i = base + lane;
        int s_mine = d;
        if (i < total) {
            s_mine = (i < deg) ? csr[o0 + i] : d;
            const float2* ap = (const float2*)(a_s + (size_t)s_mine * 10);
            float2 v0 = ap[0], v1 = ap[1], v2 = ap[2], v3 = ap[3], v4 = ap[4];
            float e;
#define DOH(h, val)                                     \
            e = __expf(lrelu((val) + add[h]));          \
            den[h] += e;                                \
            al[wid][h][lane] = e;
            DOH(0, v0.x) DOH(1, v0.y) DOH(2, v1.x) DOH(3, v1.y) DOH(4, v2.x)
            DOH(5, v2.y) DOH(6, v3.x) DOH(7, v3.y) DOH(8, v4.x) DOH(9, v4.y)
#undef DOH
        }
        __syncthreads();
        const int cnt = min(64, total - base);
        if (cnt > 0) {
            uint4 vc = {0, 0, 0, 0};
            {
                int s0 = __shfl(s_mine, 0);
                if (haveCh) vc = feat4[(size_t)s0 * 44 + L];
            }
            for (int j = 0; j < cnt; ++j) {
                float aLo = al[wid][hLo][j];
                float aHi = al[wid][hHi][j];
                uint4 v = vc;
                if (j + 1 < cnt) {
                    int sn = __shfl(s_mine, j + 1);
                    if (haveCh) vc = feat4[(size_t)sn * 44 + L];
                }
#pragma unroll
                for (int q = 0; q < 4; ++q) {
                    uint32 u = (q == 0) ? v.x : (q == 1) ? v.y : (q == 2) ? v.z : v.w;
                    float aA = (8 * L + 2 * q >= bnd) ? aHi : aLo;
                    float aB = (8 * L + 2 * q + 1 >= bnd) ? aHi : aLo;
                    acc[2 * q] = fmaf(aA, bflo(u), acc[2 * q]);
                    acc[2 * q + 1] = fmaf(aB, bfhi(u), acc[2 * q + 1]);
                }
            }
        }
        __syncthreads();
    }
    // reduce denominators across the wave
#pragma unroll
    for (int off = 32; off > 0; off >>= 1) {
#pragma unroll
        for (int h = 0; h < 10; ++h) den[h] += __shfl_xor(den[h], off);
    }
    if (lane == 0) {
#pragma unroll
        for (int h = 0; h < 10; ++h) rdn[wid][h] = 1.f / den[h];
    }
    __syncthreads();
    if (haveCh) {
        const float rLo = rdn[wid][hLo];
        const float rHi = rdn[wid][hHi];
        uint32 o[4];
#pragma unroll
        for (int q = 0; q < 4; ++q) {
            int pair = 4 * L + q;
            if (pair < 175) {
                float rA = (8 * L + 2 * q >= bnd) ? rHi : rLo;
                float rB = (8 * L + 2 * q + 1 >= bnd) ? rHi : rLo;
                float v0 = acc[2 * q] * rA + bias[2 * pair];
                float v1 = acc[2 * q + 1] * rB + bias[2 * pair + 1];
                v0 = (v0 > 0.f) ? v0 : expm1f(v0);
                v1 = (v1 > 0.f) ? v1 : expm1f(v1);
                o[q] = packbf(v0, v1);
            } else {
                o[q] = 0u;  // K-pad for gemm2
            }
        }
        uint4 ov = {o[0], o[1], o[2], o[3]};
        x2p4[(size_t)d * 44 + L] = ov;
    }
}

// ---------------- W2 -> bf16 MFMA B-fragment layout ----------------
__global__ void k_prep_w2(const float* __restrict__ W2, uint32* __restrict__ W2f) {
    int idx = blockIdx.x * blockDim.x + threadIdx.x;
    if (idx >= 11 * 8 * 64) return;
    int lane = idx & 63;
    int t = (idx >> 6) & 7;
    int kk = idx >> 9;
    int c = t * 16 + (lane & 15);
    int k0 = kk * 32 + (lane >> 4) * 8;
    uint32 o[4];
#pragma unroll
    for (int jj = 0; jj < 4; ++jj) {
        int ka = k0 + 2 * jj, kb = ka + 1;
        float va = (ka < HC1) ? W2[ka * C2 + c] : 0.f;
        float vb = (kb < HC1) ? W2[kb * C2 + c] : 0.f;
        o[jj] = packbf(va, vb);
    }
    uint32* dst = W2f + (size_t)idx * 4;
    dst[0] = o[0]; dst[1] = o[1]; dst[2] = o[2]; dst[3] = o[3];
}

// ---------------- layer 2 GEMM via MFMA, fused att dots ----------------
__global__ __launch_bounds__(256) void k_gemm2(const short* __restrict__ x2p,       // [N][352]
                                               const short8* __restrict__ W2f,
                                               const float* __restrict__ attS,
                                               const float* __restrict__ attD,
                                               unsigned short* __restrict__ h2b,    // [N][128]
                                               float* __restrict__ a_s2, float* __restrict__ a_d2) {
    const int lane = threadIdx.x & 63;
    const int wid = threadIdx.x >> 6;
    const int mtile = blockIdx.x * 4 + wid;
    if (mtile >= N_NODES / 16) return;
    const int c_lo = lane & 15, grp = lane >> 4;
    const int m0 = mtile * 16;
    const short* aptr = x2p + (size_t)(m0 + c_lo) * 352 + grp * 8;

    f32x4 acc[8];
#pragma unroll
    for (int t = 0; t < 8; ++t) acc[t] = (f32x4){0.f, 0.f, 0.f, 0.f};
#pragma unroll
    for (int kk = 0; kk < 11; ++kk) {
        short8 a = *reinterpret_cast<const short8*>(aptr + kk * 32);
#pragma unroll
        for (int t = 0; t < 8; ++t) {
            short8 b = W2f[(kk * 8 + t) * 64 + lane];
            acc[t] = __builtin_amdgcn_mfma_f32_16x16x32_bf16(a, b, acc[t], 0, 0, 0);
        }
    }
    float attSv[8], attDv[8];
#pragma unroll
    for (int t = 0; t < 8; ++t) {
        attSv[t] = attS[t * 16 + c_lo];
        attDv[t] = attD[t * 16 + c_lo];
    }
    float ps[4] = {0, 0, 0, 0}, pd[4] = {0, 0, 0, 0};
#pragma unroll
    for (int t = 0; t < 8; ++t)
#pragma unroll
        for (int r = 0; r < 4; ++r) {
            ps[r] = fmaf(acc[t][r], attSv[t], ps[r]);
            pd[r] = fmaf(acc[t][r], attDv[t], pd[r]);
        }
#pragma unroll
    for (int r = 0; r < 4; ++r) {
        int node = m0 + grp * 4 + r;
#pragma unroll
        for (int t = 0; t < 8; ++t) h2b[(size_t)node * C2 + t * 16 + c_lo] = bfbits(acc[t][r]);
    }
#pragma unroll
    for (int r = 0; r < 4; ++r) {
        float s = ps[r], dd = pd[r];
#pragma unroll
        for (int off = 1; off < 16; off <<= 1) {
            s += __shfl_xor(s, off);
            dd += __shfl_xor(dd, off);
        }
        if (c_lo == 0) {
            int node = m0 + grp * 4 + r;
            a_s2[node] = s;
            a_d2[node] = dd;
        }
    }
}

// ---------------- layer-2 aggregation + fused bias/relu/max-pool ----------------
// 4 nodes/block (1 wave each), no LDS, srcs/alpha via shfl, 4 edges per load step
__global__ __launch_bounds__(256) void k_agg2(const uint4* __restrict__ feat4,  // h2b [N][16] x16B
                                              const float* __restrict__ a_s,   // [N]
                                              const float* __restrict__ a_d,
                                              const int* __restrict__ offs,
                                              const int* __restrict__ csr,
                                              const float* __restrict__ b2,    // [128]
                                              const int* __restrict__ batch,
                                              float* __restrict__ pooled) {    // [G][128]
    const int lane = threadIdx.x & 63;
    const int wid = threadIdx.x >> 6;
    const int d = blockIdx.x * 4 + wid;
    const int o0 = offs[d];
    const int deg = offs[d + 1] - o0;
    const int total = deg + 1;
    const float add = a_d[d];
    const int g = lane >> 4, cl = lane & 15;

    float acc[8];
#pragma unroll
    for (int q = 0; q < 8; ++q) acc[q] = 0.f;
    float den = 0.f;

    for (int base = 0; base < total; base += 64) {
        const int i = base + lane;
        int s_mine = d;
        float e_mine = 0.f;
        if (i < total) {
            s_mine = (i < deg) ? csr[o0 + i] : d;
            e_mine = __expf(lrelu(a_s[s_mine] + add));
            den += e_mine;
        }
        const int cnt = min(64, total - base);
        // 4 edges per step; group g handles edge jb+g
        int sj = __shfl(s_mine, g);
        float aj = __shfl(e_mine, g);
        uint4 vc = feat4[(size_t)sj * 16 + cl];
        for (int jb = 0; jb < cnt; jb += 4) {
            uint4 v = vc;
            float a = aj;
            if (jb + 4 < cnt) {
                int ni = jb + 4 + g;
                int sn = __shfl(s_mine, ni);
                aj = __shfl(e_mine, ni);
                vc = feat4[(size_t)sn * 16 + cl];
            }
            acc[0] = fmaf(a, bflo(v.x), acc[0]);
            acc[1] = fmaf(a, bfhi(v.x), acc[1]);
            acc[2] = fmaf(a, bflo(v.y), acc[2]);
            acc[3] = fmaf(a, bfhi(v.y), acc[3]);
            acc[4] = fmaf(a, bflo(v.z), acc[4]);
            acc[5] = fmaf(a, bfhi(v.z), acc[5]);
            acc[6] = fmaf(a, bflo(v.w), acc[6]);
            acc[7] = fmaf(a, bfhi(v.w), acc[7]);
        }
    }
    // combine the 4 edge-groups
#pragma unroll
    for (int q = 0; q < 8; ++q) {
        acc[q] += __shfl_xor(acc[q], 16);
        acc[q] += __shfl_xor(acc[q], 32);
    }
#pragma unroll
    for (int off = 32; off > 0; off >>= 1) den += __shfl_xor(den, off);

    if (lane < 16) {
        const float rden = 1.f / den;
        const int b = batch[d];
        const float4* bp = (const float4*)(b2 + 8 * lane);
        float4 b0 = bp[0], b1 = bp[1];
        float vals[8];
        vals[0] = b0.x; vals[1] = b0.y; vals[2] = b0.z; vals[3] = b0.w;
        vals[4] = b1.x; vals[5] = b1.y; vals[6] = b1.z; vals[7] = b1.w;
#pragma unroll
        for (int q = 0; q < 8; ++q) {
            float v = fmaxf(acc[q] * rden + vals[q], 0.f);
            atomicMax((int*)&pooled[b * C2 + 8 * lane + q], __float_as_int(v));
        }
    }
}

// ---------------- dense head ----------------
__global__ __launch_bounds__(128) void k_head(const float* __restrict__ pooled,
                                              const float* __restrict__ Wg,
                                              const float* __restrict__ bg,
                                              const float* __restrict__ Wo,
                                              const float* __restrict__ bo,
                                              float* __restrict__ out) {
    __shared__ float p[C2];
    __shared__ float wsum[2];
    const int g = blockIdx.x;
    const int tid = threadIdx.x;
    p[tid] = pooled[g * C2 + tid];
    __syncthreads();
    float acc = bg[tid];
#pragma unroll 8
    for (int k = 0; k < C2; ++k) acc = fmaf(p[k], Wg[k * C2 + tid], acc);
    float z = fmaxf(acc, 0.f);
    float prod = z * Wo[tid];
#pragma unroll
    for (int off = 32; off; off >>= 1) prod += __shfl_down(prod, off);
    if ((tid & 63) == 0) wsum[tid >> 6] = prod;
    __syncthreads();
    if (tid == 0) out[g] = wsum[0] + wsum[1] + bo[0];
}

extern "C" void kernel_launch(void* const* d_in, const int* in_sizes, int n_in,
                              void* d_out, int out_size, void* d_ws, size_t ws_size,
                              hipStream_t stream) {
    const float* x        = (const float*)d_in[0];
    const int*   ei       = (const int*)d_in[1];
    const int*   batch    = (const int*)d_in[2];
    const float* W1       = (const float*)d_in[3];
    const float* att_src1 = (const float*)d_in[4];
    const float* att_dst1 = (const float*)d_in[5];
    const float* b1       = (const float*)d_in[6];
    const float* W2       = (const float*)d_in[7];
    const float* att_src2 = (const float*)d_in[8];
    const float* att_dst2 = (const float*)d_in[9];
    const float* b2       = (const float*)d_in[10];
    const float* Wg       = (const float*)d_in[11];
    const float* bg       = (const float*)d_in[12];
    const float* Wo       = (const float*)d_in[13];
    const float* bo       = (const float*)d_in[14];
    const int* src = ei;
    const int* dst = ei + N_EDGES;

    char* ws = (char*)d_ws;
    size_t off = 0;
    auto alloc = [&](size_t bytes) -> char* {
        char* p = ws + off;
        off = (off + bytes + 255) & ~(size_t)255;
        return p;
    };
    int*    deg    = (int*)alloc((size_t)N_NODES * 4);
    int*    offs   = (int*)alloc((size_t)(N_NODES + 1) * 4);
    int*    cursor = (int*)alloc((size_t)N_NODES * 4);
    int*    csr    = (int*)alloc((size_t)N_EDGES * 4);
    float*  a_s1   = (float*)alloc((size_t)N_NODES * H1 * 4);
    float*  a_d1   = (float*)alloc((size_t)N_NODES * H1 * 4);
    float*  a_s2   = (float*)alloc((size_t)N_NODES * 4);
    float*  a_d2   = (float*)alloc((size_t)N_NODES * 4);
    float*  pooled = (float*)alloc((size_t)N_GRAPHS * C2 * 4);
    uint32* xbf    = (uint32*)alloc((size_t)N_NODES * 32 * 4);      // [N][64] bf16
    unsigned short* h1b = (unsigned short*)alloc((size_t)N_NODES * 352 * 2);
    uint32* x2p    = (uint32*)alloc((size_t)N_NODES * 176 * 4);     // [N][352] bf16
    unsigned short* h2b = (unsigned short*)alloc((size_t)N_NODES * C2 * 2);
    uint32* W1f    = (uint32*)alloc((size_t)2 * 24 * 64 * 16);
    uint32* W2f    = (uint32*)alloc((size_t)11 * 8 * 64 * 16);

    hipMemsetAsync(deg, 0, (size_t)N_NODES * 4, stream);
    hipMemsetAsync(pooled, 0, (size_t)N_GRAPHS * C2 * 4, stream);

    k_count<<<(N_EDGES + 255) / 256, 256, 0, stream>>>(dst, deg);
    k_scan<<<1, 1024, 0, stream>>>(deg, offs, cursor);
    k_fill<<<(N_EDGES + 255) / 256, 256, 0, stream>>>(src, dst, cursor, csr);

    k_xbf<<<(N_NODES * 8 + 255) / 256, 256, 0, stream>>>(x, xbf);
    k_prep_w1<<<(2 * 24 * 64 + 255) / 256, 256, 0, stream>>>(W1, att_src1, att_dst1, W1f);
    k_prep_w2<<<(11 * 8 * 64 + 255) / 256, 256, 0, stream>>>(W2, W2f);

    k_gemm1<<<(N_NODES / 16 + 3) / 4, 256, 0, stream>>>((const short*)xbf, (const short8*)W1f,
                                                        h1b, a_s1, a_d1);

    k_agg1<<<N_NODES / 4, 256, 0, stream>>>((const uint4*)h1b, a_s1, a_d1, offs, csr, b1,
                                            (uint4*)x2p);

    k_gemm2<<<(N_NODES / 16 + 3) / 4, 256, 0, stream>>>((const short*)x2p, (const short8*)W2f,
                                                        att_src2, att_dst2, h2b, a_s2, a_d2);

    k_agg2<<<N_NODES / 4, 256, 0, stream>>>((const uint4*)h2b, a_s2, a_d2, offs, csr, b2,
                                            batch, pooled);

    k_head<<<N_GRAPHS, 128, 0, stream>>>(pooled, Wg, bg, Wo, bo, (float*)d_out);
}

// Round 4
// 402.352 us; speedup vs baseline: 2.7187x; 1.2546x over previous
//
#include <hip/hip_runtime.h>
#include <hip/hip_bf16.h>
#include <cmath>

#define N_NODES 50000
#define N_EDGES 800000
#define N_GRAPHS 1024
#define F_IN 35
#define H1 10
#define C1 35
#define HC1 350
#define C2 128
#define NB256 196   // ceil(N_NODES/256)

typedef unsigned int uint32;
typedef __attribute__((ext_vector_type(8))) short short8;
typedef __attribute__((ext_vector_type(4))) float f32x4;

static __device__ __forceinline__ float bflo(uint32 u) { return __uint_as_float(u << 16); }
static __device__ __forceinline__ float bfhi(uint32 u) { return __uint_as_float(u & 0xffff0000u); }
static __device__ __forceinline__ unsigned short bfbits(float f) {
    return __builtin_bit_cast(unsigned short, __float2bfloat16(f));
}
static __device__ __forceinline__ uint32 packbf(float a, float b) {
    return ((uint32)bfbits(b) << 16) | (uint32)bfbits(a);
}
static __device__ __forceinline__ float lrelu(float e) { return (e > 0.f) ? e : 0.2f * e; }

// ---------------- CSR: count ----------------
__global__ void k_count(const int* __restrict__ dst, int* __restrict__ deg) {
    int e = blockIdx.x * blockDim.x + threadIdx.x;
    if (e < N_EDGES) atomicAdd(&deg[dst[e]], 1);
}

// ---------------- CSR: hierarchical scan ----------------
__global__ __launch_bounds__(256) void k_bsum(const int* __restrict__ deg, int* __restrict__ bsum) {
    const int i = blockIdx.x * 256 + threadIdx.x;
    int v = (i < N_NODES) ? deg[i] : 0;
#pragma unroll
    for (int off = 32; off; off >>= 1) v += __shfl_xor(v, off);
    __shared__ int ws[4];
    if ((threadIdx.x & 63) == 0) ws[threadIdx.x >> 6] = v;
    __syncthreads();
    if (threadIdx.x == 0) bsum[blockIdx.x] = ws[0] + ws[1] + ws[2] + ws[3];
}

__global__ __launch_bounds__(256) void k_bscan(const int* __restrict__ bsum, int* __restrict__ bpre) {
    __shared__ int buf[256];
    const int t = threadIdx.x;
    int v = (t < NB256) ? bsum[t] : 0;
    buf[t] = v;
    __syncthreads();
    for (int off = 1; off < 256; off <<= 1) {
        int u = (t >= off) ? buf[t - off] : 0;
        __syncthreads();
        buf[t] += u;
        __syncthreads();
    }
    if (t < NB256) bpre[t] = buf[t] - v;  // exclusive
}

__global__ __launch_bounds__(256) void k_boffs(const int* __restrict__ deg,
                                               const int* __restrict__ bpre,
                                               int* __restrict__ offs, int* __restrict__ cursor) {
    const int b = blockIdx.x, t = threadIdx.x;
    const int i = b * 256 + t;
    const int lane = t & 63, wid = t >> 6;
    int v = (i < N_NODES) ? deg[i] : 0;
    int s = v;
#pragma unroll
    for (int off = 1; off < 64; off <<= 1) {
        int u = __shfl_up(s, off);
        if (lane >= off) s += u;
    }
    __shared__ int wsum[4];
    if (lane == 63) wsum[wid] = s;
    __syncthreads();
    int wbase = 0;
    for (int w = 0; w < wid; ++w) wbase += wsum[w];
    int excl = bpre[b] + wbase + s - v;
    if (i < N_NODES) { offs[i] = excl; cursor[i] = excl; }
    if (i == 0) offs[N_NODES] = N_EDGES;
}

__global__ void k_fill(const int* __restrict__ src, const int* __restrict__ dst,
                       int* __restrict__ cursor, int* __restrict__ csr) {
    int e = blockIdx.x * blockDim.x + threadIdx.x;
    if (e < N_EDGES) {
        int p = atomicAdd(&cursor[dst[e]], 1);
        csr[p] = src[e];
    }
}

// ---------------- fused prep: x->bf16 pad, W1(+att folds)->frag, W2->frag ----------------
#define XBLK ((N_NODES * 8 + 255) / 256)
__global__ __launch_bounds__(256) void k_prep(const float* __restrict__ x,
                                              const float* __restrict__ W1,
                                              const float* __restrict__ attS1,
                                              const float* __restrict__ attD1,
                                              const float* __restrict__ W2,
                                              uint32* __restrict__ xbf,
                                              uint32* __restrict__ W1f,
                                              uint32* __restrict__ W2f) {
    const int b = blockIdx.x, t = threadIdx.x;
    if (b < XBLK) {
        int idx = b * 256 + t;
        if (idx >= N_NODES * 8) return;
        int n = idx >> 3, tt = idx & 7;
        uint32 o[4];
#pragma unroll
        for (int p = 0; p < 4; ++p) {
            int k0 = tt * 8 + 2 * p;
            float a = (k0 < F_IN) ? x[(size_t)n * F_IN + k0] : 0.f;
            float bb = (k0 + 1 < F_IN) ? x[(size_t)n * F_IN + k0 + 1] : 0.f;
            o[p] = packbf(a, bb);
        }
        uint32* d = xbf + (size_t)n * 32 + tt * 4;
        d[0] = o[0]; d[1] = o[1]; d[2] = o[2]; d[3] = o[3];
    } else if (b < XBLK + 12) {
        int idx = (b - XBLK) * 256 + t;
        if (idx >= 2 * 24 * 64) return;
        int lane = idx & 63;
        int tt = (idx >> 6) % 24;
        int kk = idx / (24 * 64);
        int c = tt * 16 + (lane & 15);
        int k0 = kk * 32 + (lane >> 4) * 8;
        uint32 o[4];
#pragma unroll
        for (int jj = 0; jj < 4; ++jj) {
            float v[2];
#pragma unroll
            for (int half = 0; half < 2; ++half) {
                int k = k0 + 2 * jj + half;
                float val = 0.f;
                if (k < F_IN) {
                    if (c < HC1) {
                        val = W1[k * HC1 + c];
                    } else if (c >= 352 && c < 362) {
                        int h = c - 352;
                        float s = 0.f;
                        for (int cc = 0; cc < C1; ++cc)
                            s = fmaf(W1[k * HC1 + h * C1 + cc], attS1[h * C1 + cc], s);
                        val = s;
                    } else if (c >= 368 && c < 378) {
                        int h = c - 368;
                        float s = 0.f;
                        for (int cc = 0; cc < C1; ++cc)
                            s = fmaf(W1[k * HC1 + h * C1 + cc], attD1[h * C1 + cc], s);
                        val = s;
                    }
                }
                v[half] = val;
            }
            o[jj] = packbf(v[0], v[1]);
        }
        uint32* d = W1f + (size_t)idx * 4;
        d[0] = o[0]; d[1] = o[1]; d[2] = o[2]; d[3] = o[3];
    } else {
        int idx = (b - XBLK - 12) * 256 + t;
        if (idx >= 11 * 8 * 64) return;
        int lane = idx & 63;
        int tt = (idx >> 6) & 7;
        int kk = idx >> 9;
        int c = tt * 16 + (lane & 15);
        int k0 = kk * 32 + (lane >> 4) * 8;
        uint32 o[4];
#pragma unroll
        for (int jj = 0; jj < 4; ++jj) {
            int ka = k0 + 2 * jj, kb = ka + 1;
            float va = (ka < HC1) ? W2[ka * C2 + c] : 0.f;
            float vb = (kb < HC1) ? W2[kb * C2 + c] : 0.f;
            o[jj] = packbf(va, vb);
        }
        uint32* d = W2f + (size_t)idx * 4;
        d[0] = o[0]; d[1] = o[1]; d[2] = o[2]; d[3] = o[3];
    }
}

// ---------------- layer-1 GEMM via MFMA: h1b = x@W1 (bf16), a_s1/a_d1 fused ----------------
__global__ __launch_bounds__(256) void k_gemm1(const short* __restrict__ xbf,      // [N][64]
                                               const short8* __restrict__ W1f,
                                               unsigned short* __restrict__ h1b,   // [N][352]
                                               float* __restrict__ a_s1,           // [N][10]
                                               float* __restrict__ a_d1) {
    const int lane = threadIdx.x & 63;
    const int wid = threadIdx.x >> 6;
    const int mtile = blockIdx.x * 4 + wid;
    if (mtile >= N_NODES / 16) return;
    const int c_lo = lane & 15, grp = lane >> 4;
    const int m0 = mtile * 16;
    const short* aptr = xbf + (size_t)(m0 + c_lo) * 64 + grp * 8;

    f32x4 acc[24];
#pragma unroll
    for (int t = 0; t < 24; ++t) acc[t] = (f32x4){0.f, 0.f, 0.f, 0.f};
#pragma unroll
    for (int kk = 0; kk < 2; ++kk) {
        short8 a = *reinterpret_cast<const short8*>(aptr + kk * 32);
#pragma unroll
        for (int t = 0; t < 24; ++t) {
            short8 b = W1f[(kk * 24 + t) * 64 + lane];
            acc[t] = __builtin_amdgcn_mfma_f32_16x16x32_bf16(a, b, acc[t], 0, 0, 0);
        }
    }
#pragma unroll
    for (int r = 0; r < 4; ++r) {
        int node = m0 + grp * 4 + r;
#pragma unroll
        for (int t = 0; t < 22; ++t)
            h1b[(size_t)node * 352 + t * 16 + c_lo] = bfbits(acc[t][r]);
        if (c_lo < 10) {
            a_s1[node * 10 + c_lo] = acc[22][r];
            a_d1[node * 10 + c_lo] = acc[23][r];
        }
    }
}

// ---------------- layer-1 aggregation: 4 nodes/block; 4 edge-groups x 16 lanes ----------------
// lane cl of group g covers uint4 slots {cl, cl+16, cl+32(<44)} of the 44-slot row
__global__ __launch_bounds__(256) void k_agg1(const uint4* __restrict__ feat4,  // h1b [N][44]
                                              const float* __restrict__ a_s,   // [N][10]
                                              const float* __restrict__ a_d,
                                              const int* __restrict__ offs,
                                              const int* __restrict__ csr,
                                              const float* __restrict__ bias,  // [350]
                                              uint4* __restrict__ x2p4) {      // [N][44]
    __shared__ float al[4][10][72];
    __shared__ float rdn[4][10];
    __shared__ int totmax[4];
    const int tid = threadIdx.x;
    const int lane = tid & 63, wid = tid >> 6;
    const int d = blockIdx.x * 4 + wid;
    const int o0 = offs[d];
    const int deg = offs[d + 1] - o0;
    const int total = deg + 1;  // self-loop as edge 'deg'
    const int cl = lane & 15, g = lane >> 4;

    if (lane < 8) {
#pragma unroll
        for (int h = 0; h < 10; ++h) al[wid][h][64 + lane] = 0.f;  // pad slots stay zero
    }
    if (lane == 0) totmax[wid] = total;
    __syncthreads();
    const int tmx = max(max(totmax[0], totmax[1]), max(totmax[2], totmax[3]));
    const int rounds = (tmx + 63) >> 6;

    float add[10];
    {
        const float2* ap = (const float2*)(a_d + (size_t)d * 10);
#pragma unroll
        for (int p = 0; p < 5; ++p) { float2 v = ap[p]; add[2 * p] = v.x; add[2 * p + 1] = v.y; }
    }
    // slot geometry (compile-time-ish per lane)
    const int u0 = cl, u1 = cl + 16, u2 = cl + 32;
    const bool has2 = (u2 < 44);
    const int hLo0 = (8 * u0) / 35, hHi0 = min((8 * u0 + 7) / 35, 9), bnd0 = 35 * hHi0;
    const int hLo1 = (8 * u1) / 35, hHi1 = min((8 * u1 + 7) / 35, 9), bnd1 = 35 * hHi1;
    const int hLo2 = has2 ? (8 * u2) / 35 : 0, hHi2 = has2 ? min((8 * u2 + 7) / 35, 9) : 0;
    const int bnd2 = 35 * hHi2;

    float acc0[8], acc1[8], acc2[8];
#pragma unroll
    for (int q = 0; q < 8; ++q) { acc0[q] = 0.f; acc1[q] = 0.f; acc2[q] = 0.f; }
    float den[10];
#pragma unroll
    for (int h = 0; h < 10; ++h) den[h] = 0.f;

    for (int rb = 0; rb < rounds; ++rb) {
        const int base = rb << 6;
        const int i = base + lane;
        int s_mine = d;
        if (i < total) {
            s_mine = (i < deg) ? csr[o0 + i] : d;
            const float2* ap = (const float2*)(a_s + (size_t)s_mine * 10);
            float2 v0 = ap[0], v1 = ap[1], v2 = ap[2], v3 = ap[3], v4 = ap[4];
            float e;
#define DOH(h, val)                            \
            e = __expf(lrelu((val) + add[h])); \
            den[h] += e;                       \
            al[wid][h][lane] = e;
            DOH(0, v0.x) DOH(1, v0.y) DOH(2, v1.x) DOH(3, v1.y) DOH(4, v2.x)
            DOH(5, v2.y) DOH(6, v3.x) DOH(7, v3.y) DOH(8, v4.x) DOH(9, v4.y)
#undef DOH
        } else {
#pragma unroll
            for (int h = 0; h < 10; ++h) al[wid][h][lane] = 0.f;
        }
        __syncthreads();
        const int cnt = min(64, total - base);
        if (cnt > 0) {
            int scur = __shfl(s_mine, g);
            uint4 v0 = feat4[(size_t)scur * 44 + u0];
            uint4 v1 = feat4[(size_t)scur * 44 + u1];
            uint4 v2 = has2 ? feat4[(size_t)scur * 44 + u2] : (uint4){0, 0, 0, 0};
            for (int jb = 0; jb < cnt; jb += 4) {
                uint4 w0 = v0, w1 = v1, w2 = v2;
                const int jj = jb + g;  // alpha index; zero if jj >= cnt (al pre-zeroed)
                if (jb + 4 < cnt) {
                    int sn = __shfl(s_mine, jb + 4 + g);
                    v0 = feat4[(size_t)sn * 44 + u0];
                    v1 = feat4[(size_t)sn * 44 + u1];
                    if (has2) v2 = feat4[(size_t)sn * 44 + u2];
                }
#define ACCSLOT(ACC, W, HLO, HHI, BND, U)                                   \
                {                                                           \
                    float aLo = al[wid][HLO][jj], aHi = al[wid][HHI][jj];   \
                    _Pragma("unroll")                                       \
                    for (int q = 0; q < 4; ++q) {                           \
                        uint32 u = (q == 0) ? W.x : (q == 1) ? W.y : (q == 2) ? W.z : W.w; \
                        float aA = (8 * (U) + 2 * q >= (BND)) ? aHi : aLo;  \
                        float aB = (8 * (U) + 2 * q + 1 >= (BND)) ? aHi : aLo; \
                        ACC[2 * q] = fmaf(aA, bflo(u), ACC[2 * q]);         \
                        ACC[2 * q + 1] = fmaf(aB, bfhi(u), ACC[2 * q + 1]); \
                    }                                                       \
                }
                ACCSLOT(acc0, w0, hLo0, hHi0, bnd0, u0)
                ACCSLOT(acc1, w1, hLo1, hHi1, bnd1, u1)
                if (has2) ACCSLOT(acc2, w2, hLo2, hHi2, bnd2, u2)
#undef ACCSLOT
            }
        }
        __syncthreads();
    }
    // combine 4 edge-groups
#pragma unroll
    for (int q = 0; q < 8; ++q) {
        acc0[q] += __shfl_xor(acc0[q], 16); acc0[q] += __shfl_xor(acc0[q], 32);
        acc1[q] += __shfl_xor(acc1[q], 16); acc1[q] += __shfl_xor(acc1[q], 32);
        acc2[q] += __shfl_xor(acc2[q], 16); acc2[q] += __shfl_xor(acc2[q], 32);
    }
#pragma unroll
    for (int off = 32; off > 0; off >>= 1) {
#pragma unroll
        for (int h = 0; h < 10; ++h) den[h] += __shfl_xor(den[h], off);
    }
    if (lane == 0) {
#pragma unroll
        for (int h = 0; h < 10; ++h) rdn[wid][h] = 1.f / den[h];
    }
    __syncthreads();
    if (g == 0) {
#define EPI(ACC, HLO, HHI, BND, U)                                          \
        {                                                                   \
            float rLo = rdn[wid][HLO], rHi = rdn[wid][HHI];                 \
            uint32 o[4];                                                    \
            _Pragma("unroll")                                               \
            for (int q = 0; q < 4; ++q) {                                   \
                int p = 4 * (U) + q;                                        \
                if (p < 175) {                                              \
                    int ch0 = 8 * (U) + 2 * q;                              \
                    float rA = (ch0 >= (BND)) ? rHi : rLo;                  \
                    float rB = (ch0 + 1 >= (BND)) ? rHi : rLo;              \
                    float v0 = ACC[2 * q] * rA + bias[ch0];                 \
                    float v1 = ACC[2 * q + 1] * rB + bias[ch0 + 1];         \
                    v0 = (v0 > 0.f) ? v0 : expm1f(v0);                      \
                    v1 = (v1 > 0.f) ? v1 : expm1f(v1);                      \
                    o[q] = packbf(v0, v1);                                  \
                } else {                                                    \
                    o[q] = 0u;                                              \
                }                                                           \
            }                                                               \
            uint4 ov = {o[0], o[1], o[2], o[3]};                            \
            x2p4[(size_t)d * 44 + (U)] = ov;                                \
        }
        EPI(acc0, hLo0, hHi0, bnd0, u0)
        EPI(acc1, hLo1, hHi1, bnd1, u1)
        if (has2) EPI(acc2, hLo2, hHi2, bnd2, u2)
#undef EPI
    }
}

// ---------------- layer 2 GEMM via MFMA, fused att dots ----------------
__global__ __launch_bounds__(256) void k_gemm2(const short* __restrict__ x2p,       // [N][352]
                                               const short8* __restrict__ W2f,
                                               const float* __restrict__ attS,
                                               const float* __restrict__ attD,
                                               unsigned short* __restrict__ h2b,    // [N][128]
                                               float* __restrict__ a_s2, float* __restrict__ a_d2) {
    const int lane = threadIdx.x & 63;
    const int wid = threadIdx.x >> 6;
    const int mtile = blockIdx.x * 4 + wid;
    if (mtile >= N_NODES / 16) return;
    const int c_lo = lane & 15, grp = lane >> 4;
    const int m0 = mtile * 16;
    const short* aptr = x2p + (size_t)(m0 + c_lo) * 352 + grp * 8;

    f32x4 acc[8];
#pragma unroll
    for (int t = 0; t < 8; ++t) acc[t] = (f32x4){0.f, 0.f, 0.f, 0.f};
#pragma unroll
    for (int kk = 0; kk < 11; ++kk) {
        short8 a = *reinterpret_cast<const short8*>(aptr + kk * 32);
#pragma unroll
        for (int t = 0; t < 8; ++t) {
            short8 b = W2f[(kk * 8 + t) * 64 + lane];
            acc[t] = __builtin_amdgcn_mfma_f32_16x16x32_bf16(a, b, acc[t], 0, 0, 0);
        }
    }
    float attSv[8], attDv[8];
#pragma unroll
    for (int t = 0; t < 8; ++t) {
        attSv[t] = attS[t * 16 + c_lo];
        attDv[t] = attD[t * 16 + c_lo];
    }
    float ps[4] = {0, 0, 0, 0}, pd[4] = {0, 0, 0, 0};
#pragma unroll
    for (int t = 0; t < 8; ++t)
#pragma unroll
        for (int r = 0; r < 4; ++r) {
            ps[r] = fmaf(acc[t][r], attSv[t], ps[r]);
            pd[r] = fmaf(acc[t][r], attDv[t], pd[r]);
        }
#pragma unroll
    for (int r = 0; r < 4; ++r) {
        int node = m0 + grp * 4 + r;
#pragma unroll
        for (int t = 0; t < 8; ++t) h2b[(size_t)node * C2 + t * 16 + c_lo] = bfbits(acc[t][r]);
    }
#pragma unroll
    for (int r = 0; r < 4; ++r) {
        float s = ps[r], dd = pd[r];
#pragma unroll
        for (int off = 1; off < 16; off <<= 1) {
            s += __shfl_xor(s, off);
            dd += __shfl_xor(dd, off);
        }
        if (c_lo == 0) {
            int node = m0 + grp * 4 + r;
            a_s2[node] = s;
            a_d2[node] = dd;
        }
    }
}

// ---------------- layer-2 aggregation -> out2 fp32 (bias+relu), no atomics ----------------
__global__ __launch_bounds__(256) void k_agg2(const uint4* __restrict__ feat4,  // h2b [N][16]
                                              const float* __restrict__ a_s,   // [N]
                                              const float* __restrict__ a_d,
                                              const int* __restrict__ offs,
                                              const int* __restrict__ csr,
                                              const float* __restrict__ b2,    // [128]
                                              float* __restrict__ out2) {      // [N][128]
    const int lane = threadIdx.x & 63;
    const int wid = threadIdx.x >> 6;
    const int d = blockIdx.x * 4 + wid;
    const int o0 = offs[d];
    const int deg = offs[d + 1] - o0;
    const int total = deg + 1;
    const float add = a_d[d];
    const int g = lane >> 4, cl = lane & 15;

    float acc[8];
#pragma unroll
    for (int q = 0; q < 8; ++q) acc[q] = 0.f;
    float den = 0.f;

    for (int base = 0; base < total; base += 64) {
        const int i = base + lane;
        int s_mine = d;
        float e_mine = 0.f;
        if (i < total) {
            s_mine = (i < deg) ? csr[o0 + i] : d;
            e_mine = __expf(lrelu(a_s[s_mine] + add));
            den += e_mine;
        }
        const int cnt = min(64, total - base);
        int sj = __shfl(s_mine, g);
        float aj = __shfl(e_mine, g);
        uint4 vc = feat4[(size_t)sj * 16 + cl];
        for (int jb = 0; jb < cnt; jb += 4) {
            uint4 v = vc;
            float a = aj;
            if (jb + 4 < cnt) {
                int ni = jb + 4 + g;
                int sn = __shfl(s_mine, ni);
                aj = __shfl(e_mine, ni);
                vc = feat4[(size_t)sn * 16 + cl];
            }
            acc[0] = fmaf(a, bflo(v.x), acc[0]);
            acc[1] = fmaf(a, bfhi(v.x), acc[1]);
            acc[2] = fmaf(a, bflo(v.y), acc[2]);
            acc[3] = fmaf(a, bfhi(v.y), acc[3]);
            acc[4] = fmaf(a, bflo(v.z), acc[4]);
            acc[5] = fmaf(a, bfhi(v.z), acc[5]);
            acc[6] = fmaf(a, bflo(v.w), acc[6]);
            acc[7] = fmaf(a, bfhi(v.w), acc[7]);
        }
    }
#pragma unroll
    for (int q = 0; q < 8; ++q) {
        acc[q] += __shfl_xor(acc[q], 16);
        acc[q] += __shfl_xor(acc[q], 32);
    }
#pragma unroll
    for (int off = 32; off > 0; off >>= 1) den += __shfl_xor(den, off);

    if (lane < 16) {
        const float rden = 1.f / den;
        const float4* bp = (const float4*)(b2 + 8 * cl);
        float4 b0 = bp[0], b1 = bp[1];
        float4 o0v, o1v;
        o0v.x = fmaxf(acc[0] * rden + b0.x, 0.f);
        o0v.y = fmaxf(acc[1] * rden + b0.y, 0.f);
        o0v.z = fmaxf(acc[2] * rden + b0.z, 0.f);
        o0v.w = fmaxf(acc[3] * rden + b0.w, 0.f);
        o1v.x = fmaxf(acc[4] * rden + b1.x, 0.f);
        o1v.y = fmaxf(acc[5] * rden + b1.y, 0.f);
        o1v.z = fmaxf(acc[6] * rden + b1.z, 0.f);
        o1v.w = fmaxf(acc[7] * rden + b1.w, 0.f);
        float4* op = (float4*)(out2 + (size_t)d * C2 + 8 * cl);
        op[0] = o0v;
        op[1] = o1v;
    }
}

// ---------------- pooling: sorted-batch run-length max, atomics at boundaries only ----------------
__global__ __launch_bounds__(128) void k_pool(const float* __restrict__ out2,
                                              const int* __restrict__ batch,
                                              float* __restrict__ pooled) {
    const int c = threadIdx.x;
    const int n0 = blockIdx.x * 50;
    const int n1 = min(n0 + 50, N_NODES);
    int curB = batch[n0];
    float curM = 0.f;
    float v = out2[(size_t)n0 * C2 + c];
    for (int n = n0; n < n1; ++n) {
        float cur = v;
        int b = batch[n];
        if (n + 1 < n1) v = out2[(size_t)(n + 1) * C2 + c];
        if (b != curB) {
            atomicMax((int*)&pooled[curB * C2 + c], __float_as_int(curM));
            curB = b;
            curM = cur;
        } else {
            curM = fmaxf(curM, cur);
        }
    }
    atomicMax((int*)&pooled[curB * C2 + c], __float_as_int(curM));
}

// ---------------- dense head ----------------
__global__ __launch_bounds__(128) void k_head(const float* __restrict__ pooled,
                                              const float* __restrict__ Wg,
                                              const float* __restrict__ bg,
                                              const float* __restrict__ Wo,
                                              const float* __restrict__ bo,
                                              float* __restrict__ out) {
    __shared__ float p[C2];
    __shared__ float wsum[2];
    const int g = blockIdx.x;
    const int tid = threadIdx.x;
    p[tid] = pooled[g * C2 + tid];
    __syncthreads();
    float acc = bg[tid];
#pragma unroll 8
    for (int k = 0; k < C2; ++k) acc = fmaf(p[k], Wg[k * C2 + tid], acc);
    float z = fmaxf(acc, 0.f);
    float prod = z * Wo[tid];
#pragma unroll
    for (int off = 32; off; off >>= 1) prod += __shfl_down(prod, off);
    if ((tid & 63) == 0) wsum[tid >> 6] = prod;
    __syncthreads();
    if (tid == 0) out[g] = wsum[0] + wsum[1] + bo[0];
}

extern "C" void kernel_launch(void* const* d_in, const int* in_sizes, int n_in,
                              void* d_out, int out_size, void* d_ws, size_t ws_size,
                              hipStream_t stream) {
    const float* x        = (const float*)d_in[0];
    const int*   ei       = (const int*)d_in[1];
    const int*   batch    = (const int*)d_in[2];
    const float* W1       = (const float*)d_in[3];
    const float* att_src1 = (const float*)d_in[4];
    const float* att_dst1 = (const float*)d_in[5];
    const float* b1       = (const float*)d_in[6];
    const float* W2       = (const float*)d_in[7];
    const float* att_src2 = (const float*)d_in[8];
    const float* att_dst2 = (const float*)d_in[9];
    const float* b2       = (const float*)d_in[10];
    const float* Wg       = (const float*)d_in[11];
    const float* bg       = (const float*)d_in[12];
    const float* Wo       = (const float*)d_in[13];
    const float* bo       = (const float*)d_in[14];
    const int* src = ei;
    const int* dst = ei + N_EDGES;

    char* ws = (char*)d_ws;
    size_t off = 0;
    auto alloc = [&](size_t bytes) -> char* {
        char* p = ws + off;
        off = (off + bytes + 255) & ~(size_t)255;
        return p;
    };
    int*    deg    = (int*)alloc((size_t)N_NODES * 4);
    int*    offs   = (int*)alloc((size_t)(N_NODES + 1) * 4);
    int*    cursor = (int*)alloc((size_t)N_NODES * 4);
    int*    csr    = (int*)alloc((size_t)N_EDGES * 4);
    int*    bsum   = (int*)alloc((size_t)NB256 * 4);
    int*    bpre   = (int*)alloc((size_t)NB256 * 4);
    float*  a_s1   = (float*)alloc((size_t)N_NODES * H1 * 4);
    float*  a_d1   = (float*)alloc((size_t)N_NODES * H1 * 4);
    float*  a_s2   = (float*)alloc((size_t)N_NODES * 4);
    float*  a_d2   = (float*)alloc((size_t)N_NODES * 4);
    float*  pooled = (float*)alloc((size_t)N_GRAPHS * C2 * 4);
    uint32* xbf    = (uint32*)alloc((size_t)N_NODES * 32 * 4);      // [N][64] bf16
    unsigned short* h1b = (unsigned short*)alloc((size_t)N_NODES * 352 * 2);
    uint32* x2p    = (uint32*)alloc((size_t)N_NODES * 176 * 4);     // [N][352] bf16
    unsigned short* h2b = (unsigned short*)alloc((size_t)N_NODES * C2 * 2);
    uint32* W1f    = (uint32*)alloc((size_t)2 * 24 * 64 * 16);
    uint32* W2f    = (uint32*)alloc((size_t)11 * 8 * 64 * 16);
    float*  out2   = (float*)h1b;  // h1b dead after k_agg1; 25.6 MB fits in 35.2 MB

    hipMemsetAsync(deg, 0, (size_t)N_NODES * 4, stream);
    hipMemsetAsync(pooled, 0, (size_t)N_GRAPHS * C2 * 4, stream);

    k_count<<<(N_EDGES + 255) / 256, 256, 0, stream>>>(dst, deg);
    k_bsum<<<NB256, 256, 0, stream>>>(deg, bsum);
    k_bscan<<<1, 256, 0, stream>>>(bsum, bpre);
    k_boffs<<<NB256, 256, 0, stream>>>(deg, bpre, offs, cursor);
    k_fill<<<(N_EDGES + 255) / 256, 256, 0, stream>>>(src, dst, cursor, csr);

    k_prep<<<XBLK + 34, 256, 0, stream>>>(x, W1, att_src1, att_dst1, W2, xbf, W1f, W2f);

    k_gemm1<<<(N_NODES / 16 + 3) / 4, 256, 0, stream>>>((const short*)xbf, (const short8*)W1f,
                                                        h1b, a_s1, a_d1);

    k_agg1<<<N_NODES / 4, 256, 0, stream>>>((const uint4*)h1b, a_s1, a_d1, offs, csr, b1,
                                            (uint4*)x2p);

    k_gemm2<<<(N_NODES / 16 + 3) / 4, 256, 0, stream>>>((const short*)x2p, (const short8*)W2f,
                                                        att_src2, att_dst2, h2b, a_s2, a_d2);

    k_agg2<<<N_NODES / 4, 256, 0, stream>>>((const uint4*)h2b, a_s2, a_d2, offs, csr, b2, out2);

    k_pool<<<(N_NODES + 49) / 50, 128, 0, stream>>>(out2, batch, pooled);

    k_head<<<N_GRAPHS, 128, 0, stream>>>(pooled, Wg, bg, Wo, bo, (float*)d_out);
}

// Round 5
// 348.981 us; speedup vs baseline: 3.1345x; 1.1529x over previous
//
#include <hip/hip_runtime.h>
#include <hip/hip_bf16.h>
#include <cmath>

#define N_NODES 50000
#define N_EDGES 800000
#define N_GRAPHS 1024
#define F_IN 35
#define H1 10
#define C1 35
#define HC1 350
#define C2 128
#define NB256 196   // ceil(N_NODES/256)

typedef unsigned int uint32;
typedef __attribute__((ext_vector_type(8))) short short8;
typedef __attribute__((ext_vector_type(4))) float f32x4;

static __device__ __forceinline__ float bflo(uint32 u) { return __uint_as_float(u << 16); }
static __device__ __forceinline__ float bfhi(uint32 u) { return __uint_as_float(u & 0xffff0000u); }
static __device__ __forceinline__ unsigned short bfbits(float f) {
    return __builtin_bit_cast(unsigned short, __float2bfloat16(f));
}
static __device__ __forceinline__ uint32 packbf(float a, float b) {
    return ((uint32)bfbits(b) << 16) | (uint32)bfbits(a);
}
static __device__ __forceinline__ float lrelu(float e) { return (e > 0.f) ? e : 0.2f * e; }

// ---------------- CSR: count ----------------
__global__ void k_count(const int* __restrict__ dst, int* __restrict__ deg) {
    int e = blockIdx.x * blockDim.x + threadIdx.x;
    if (e < N_EDGES) atomicAdd(&deg[dst[e]], 1);
}

// ---------------- CSR: hierarchical scan ----------------
__global__ __launch_bounds__(256) void k_bsum(const int* __restrict__ deg, int* __restrict__ bsum) {
    const int i = blockIdx.x * 256 + threadIdx.x;
    int v = (i < N_NODES) ? deg[i] : 0;
#pragma unroll
    for (int off = 32; off; off >>= 1) v += __shfl_xor(v, off);
    __shared__ int ws[4];
    if ((threadIdx.x & 63) == 0) ws[threadIdx.x >> 6] = v;
    __syncthreads();
    if (threadIdx.x == 0) bsum[blockIdx.x] = ws[0] + ws[1] + ws[2] + ws[3];
}

__global__ __launch_bounds__(256) void k_bscan(const int* __restrict__ bsum, int* __restrict__ bpre) {
    __shared__ int buf[256];
    const int t = threadIdx.x;
    int v = (t < NB256) ? bsum[t] : 0;
    buf[t] = v;
    __syncthreads();
    for (int off = 1; off < 256; off <<= 1) {
        int u = (t >= off) ? buf[t - off] : 0;
        __syncthreads();
        buf[t] += u;
        __syncthreads();
    }
    if (t < NB256) bpre[t] = buf[t] - v;  // exclusive
}

__global__ __launch_bounds__(256) void k_boffs(const int* __restrict__ deg,
                                               const int* __restrict__ bpre,
                                               int* __restrict__ offs, int* __restrict__ cursor) {
    const int b = blockIdx.x, t = threadIdx.x;
    const int i = b * 256 + t;
    const int lane = t & 63, wid = t >> 6;
    int v = (i < N_NODES) ? deg[i] : 0;
    int s = v;
#pragma unroll
    for (int off = 1; off < 64; off <<= 1) {
        int u = __shfl_up(s, off);
        if (lane >= off) s += u;
    }
    __shared__ int wsum[4];
    if (lane == 63) wsum[wid] = s;
    __syncthreads();
    int wbase = 0;
    for (int w = 0; w < wid; ++w) wbase += wsum[w];
    int excl = bpre[b] + wbase + s - v;
    if (i < N_NODES) { offs[i] = excl; cursor[i] = excl; }
    if (i == 0) offs[N_NODES] = N_EDGES;
}

__global__ void k_fill(const int* __restrict__ src, const int* __restrict__ dst,
                       int* __restrict__ cursor, int* __restrict__ csr) {
    int e = blockIdx.x * blockDim.x + threadIdx.x;
    if (e < N_EDGES) {
        int p = atomicAdd(&cursor[dst[e]], 1);
        csr[p] = src[e];
    }
}

// ---------------- fused prep ----------------
// seg A: xbf [N][40] bf16 (ch<35 = x, ch35 = 1.0, rest 0)       N*5 uint4 threads
// seg B: fold [35][20] fp32 = W1 @ [attS heads | attD heads]    700 threads
// seg C: W1g frag [10][2][3][64][8] bf16 (k=35 row = b1)        3840 threads
// seg D: W2f frag [11][8][64][8] bf16                           5632 threads
#define XB ((N_NODES * 5 + 255) / 256)
__global__ __launch_bounds__(256) void k_prep(const float* __restrict__ x,
                                              const float* __restrict__ W1,
                                              const float* __restrict__ attS1,
                                              const float* __restrict__ attD1,
                                              const float* __restrict__ b1,
                                              const float* __restrict__ W2,
                                              uint32* __restrict__ xbf,
                                              float* __restrict__ fold,
                                              uint32* __restrict__ W1g,
                                              uint32* __restrict__ W2f) {
    const int b = blockIdx.x, t = threadIdx.x;
    if (b < XB) {
        int idx = b * 256 + t;
        if (idx >= N_NODES * 5) return;
        int n = idx / 5, s = idx - n * 5;
        uint32 o[4];
#pragma unroll
        for (int p = 0; p < 4; ++p) {
            int ch0 = s * 8 + 2 * p, ch1 = ch0 + 1;
            float a = (ch0 < F_IN) ? x[(size_t)n * F_IN + ch0] : (ch0 == 35 ? 1.f : 0.f);
            float bb = (ch1 < F_IN) ? x[(size_t)n * F_IN + ch1] : (ch1 == 35 ? 1.f : 0.f);
            o[p] = packbf(a, bb);
        }
        uint32* d = xbf + (size_t)idx * 4;
        d[0] = o[0]; d[1] = o[1]; d[2] = o[2]; d[3] = o[3];
    } else if (b < XB + 3) {
        int idx = (b - XB) * 256 + t;
        if (idx >= 700) return;
        int k = idx / 20, o = idx - k * 20;
        int h = (o < 10) ? o : o - 10;
        const float* att = (o < 10) ? attS1 : attD1;
        float s = 0.f;
        for (int c = 0; c < C1; ++c)
            s = fmaf(W1[k * HC1 + h * C1 + c], att[h * C1 + c], s);
        fold[k * 20 + o] = s;
    } else if (b < XB + 3 + 15) {
        int idx = (b - XB - 3) * 256 + t;
        if (idx >= 10 * 2 * 3 * 64) return;
        int lane = idx & 63;
        int rest = idx >> 6;
        int tt = rest % 3;
        int rest2 = rest / 3;
        int kk = rest2 & 1;
        int h = rest2 >> 1;
        int c = tt * 16 + (lane & 15);
        int k0 = kk * 32 + (lane >> 4) * 8;
        uint32 o[4];
#pragma unroll
        for (int jj = 0; jj < 4; ++jj) {
            float v[2];
#pragma unroll
            for (int half = 0; half < 2; ++half) {
                int k = k0 + 2 * jj + half;
                float val = 0.f;
                if (c < C1) {
                    if (k < F_IN) val = W1[k * HC1 + h * C1 + c];
                    else if (k == 35) val = b1[h * C1 + c];
                }
                v[half] = val;
            }
            o[jj] = packbf(v[0], v[1]);
        }
        uint32* d = W1g + (size_t)idx * 4;
        d[0] = o[0]; d[1] = o[1]; d[2] = o[2]; d[3] = o[3];
    } else {
        int idx = (b - XB - 3 - 15) * 256 + t;
        if (idx >= 11 * 8 * 64) return;
        int lane = idx & 63;
        int tt = (idx >> 6) & 7;
        int kk = idx >> 9;
        int c = tt * 16 + (lane & 15);
        int k0 = kk * 32 + (lane >> 4) * 8;
        uint32 o[4];
#pragma unroll
        for (int jj = 0; jj < 4; ++jj) {
            int ka = k0 + 2 * jj, kb = ka + 1;
            float va = (ka < HC1) ? W2[ka * C2 + c] : 0.f;
            float vb = (kb < HC1) ? W2[kb * C2 + c] : 0.f;
            o[jj] = packbf(va, vb);
        }
        uint32* d = W2f + (size_t)idx * 4;
        d[0] = o[0]; d[1] = o[1]; d[2] = o[2]; d[3] = o[3];
    }
}

// ---------------- attention pre-dots: a_s1/a_d1 = x @ fold (fp32) ----------------
__global__ __launch_bounds__(256) void k_att1(const float* __restrict__ x,
                                              const float* __restrict__ fold,
                                              float* __restrict__ a_s1,
                                              float* __restrict__ a_d1) {
    int idx = blockIdx.x * 256 + threadIdx.x;
    if (idx >= N_NODES * 20) return;
    int n = idx / 20, o = idx - n * 20;
    const float* xr = x + (size_t)n * F_IN;
    float acc = 0.f;
#pragma unroll
    for (int k = 0; k < F_IN; ++k) acc = fmaf(xr[k], fold[k * 20 + o], acc);
    if (o < 10) a_s1[n * 10 + o] = acc;
    else        a_d1[n * 10 + (o - 10)] = acc;
}

// ---------------- layer-1 aggregation in INPUT space (commuted with W1) ----------------
// per dst, per head h: aggx[d,h,:] = (Sum_e exp(lrelu(a_s[s]+a_d[d]))_h * x[s,:]) / den_h
// x rows are 40 bf16 (ch35==1.0 -> den arrives as channel 35 of the sum).
// 4 edge-groups x 16 lanes; u=lane&15 -> headgroup hg (heads 4/4/2) x slot sl (5 x uint4).
__global__ __launch_bounds__(256, 8) void k_aggx(const uint4* __restrict__ xbf4,  // [N][5]
                                                 const float* __restrict__ a_s,   // [N][10]
                                                 const float* __restrict__ a_d,   // [N][10]
                                                 const int* __restrict__ offs,
                                                 const int* __restrict__ csr,
                                                 uint4* __restrict__ aggx4) {     // [N*10][5]
    __shared__ float al[4][10][68];
    __shared__ float addl[4][10];
    __shared__ int totmax[4];
    const int tid = threadIdx.x, lane = tid & 63, wid = tid >> 6;
    const int d = blockIdx.x * 4 + wid;
    const int o0 = offs[d];
    const int deg = offs[d + 1] - o0;
    const int total = deg + 1;  // self-loop as edge 'deg'
    const int g = lane >> 4, u = lane & 15;
    const int hg = (u >= 10) ? 2 : ((u >= 5) ? 1 : 0);
    const int sl = u - hg * 5;
    const bool act = (u < 15);
    const int h0 = hg * 4;

    if (lane < 10) addl[wid][lane] = a_d[(size_t)d * 10 + lane];
    if (lane < 4) {
#pragma unroll
        for (int h = 0; h < 10; ++h) al[wid][h][64 + lane] = 0.f;  // jj-overrun pads
    }
    if (lane == 0) totmax[wid] = total;
    __syncthreads();
    const int tmx = max(max(totmax[0], totmax[1]), max(totmax[2], totmax[3]));
    const int rounds = (tmx + 63) >> 6;

    float acc[4][8];
#pragma unroll
    for (int a = 0; a < 4; ++a)
#pragma unroll
        for (int q = 0; q < 8; ++q) acc[a][q] = 0.f;

    for (int rb = 0; rb < rounds; ++rb) {
        const int base = rb << 6;
        const int i = base + lane;
        int s_mine = d;
        if (i < total) {
            if (i < deg) s_mine = csr[o0 + i];
            const float2* ap = (const float2*)(a_s + (size_t)s_mine * 10);
            float2 p0 = ap[0], p1 = ap[1], p2 = ap[2], p3 = ap[3], p4 = ap[4];
            al[wid][0][lane] = __expf(lrelu(p0.x + addl[wid][0]));
            al[wid][1][lane] = __expf(lrelu(p0.y + addl[wid][1]));
            al[wid][2][lane] = __expf(lrelu(p1.x + addl[wid][2]));
            al[wid][3][lane] = __expf(lrelu(p1.y + addl[wid][3]));
            al[wid][4][lane] = __expf(lrelu(p2.x + addl[wid][4]));
            al[wid][5][lane] = __expf(lrelu(p2.y + addl[wid][5]));
            al[wid][6][lane] = __expf(lrelu(p3.x + addl[wid][6]));
            al[wid][7][lane] = __expf(lrelu(p3.y + addl[wid][7]));
            al[wid][8][lane] = __expf(lrelu(p4.x + addl[wid][8]));
            al[wid][9][lane] = __expf(lrelu(p4.y + addl[wid][9]));
        } else {
#pragma unroll
            for (int h = 0; h < 10; ++h) al[wid][h][lane] = 0.f;
        }
        __syncthreads();
        const int cnt = min(64, total - base);
        if (cnt > 0) {
            int scur = __shfl(s_mine, g);
            uint4 v = act ? xbf4[(size_t)scur * 5 + sl] : (uint4){0, 0, 0, 0};
            for (int jb = 0; jb < cnt; jb += 4) {
                uint4 w = v;
                const int jj = jb + g;  // al[.][.][jj]==0 for jj>=cnt (incl. pads 64..67)
                if (jb + 4 < cnt) {
                    int sn = __shfl(s_mine, jb + 4 + g);
                    if (act) v = xbf4[(size_t)sn * 5 + sl];
                }
                float f0 = bflo(w.x), f1 = bfhi(w.x), f2 = bflo(w.y), f3 = bfhi(w.y);
                float f4 = bflo(w.z), f5 = bfhi(w.z), f6 = bflo(w.w), f7 = bfhi(w.w);
#pragma unroll
                for (int a = 0; a < 4; ++a) {
                    const int hidx = min(h0 + a, 9);  // hg2 a>=2 dead (clamped, not stored)
                    const float aj = al[wid][hidx][jj];
                    acc[a][0] = fmaf(aj, f0, acc[a][0]);
                    acc[a][1] = fmaf(aj, f1, acc[a][1]);
                    acc[a][2] = fmaf(aj, f2, acc[a][2]);
                    acc[a][3] = fmaf(aj, f3, acc[a][3]);
                    acc[a][4] = fmaf(aj, f4, acc[a][4]);
                    acc[a][5] = fmaf(aj, f5, acc[a][5]);
                    acc[a][6] = fmaf(aj, f6, acc[a][6]);
                    acc[a][7] = fmaf(aj, f7, acc[a][7]);
                }
            }
        }
        __syncthreads();
    }
    // combine the 4 edge-groups
#pragma unroll
    for (int a = 0; a < 4; ++a)
#pragma unroll
        for (int q = 0; q < 8; ++q) {
            acc[a][q] += __shfl_xor(acc[a][q], 16);
            acc[a][q] += __shfl_xor(acc[a][q], 32);
        }
    const int nh = (hg == 2) ? 2 : 4;
#pragma unroll
    for (int a = 0; a < 4; ++a) {
        float den = __shfl(acc[a][3], hg * 5 + 4);  // ch35 (pseudo-one) = denominator
        float rdn = 1.f / den;
        if (g == 0 && act && a < nh) {
            uint32 o[4];
#pragma unroll
            for (int q = 0; q < 4; ++q)
                o[q] = packbf(acc[a][2 * q] * rdn, acc[a][2 * q + 1] * rdn);
            uint4 ov = {o[0], o[1], o[2], o[3]};
            aggx4[((size_t)d * 10 + h0 + a) * 5 + sl] = ov;  // ch35 -> 1.0 (bias row mult)
        }
    }
}

// ---------------- layer-1 projection: x2p[d, h*35+c] = elu( aggx[d,h,:] @ W1g[h] ) ----------------
__global__ __launch_bounds__(256, 8) void k_gemm1b(const short* __restrict__ aggx,  // [N*10][40] (+slack)
                                                   const short8* __restrict__ W1g,
                                                   unsigned short* __restrict__ x2p) {  // [N][352]
    const int lane = threadIdx.x & 63;
    const int wid = threadIdx.x >> 6;
    const int mtile = blockIdx.x * 4 + wid;
    if (mtile >= N_NODES / 16) return;
    const int c_lo = lane & 15, grp = lane >> 4;
    const int m0 = mtile * 16;
    const size_t abase = (size_t)(m0 + c_lo) * 400 + grp * 8;

#pragma unroll
    for (int h = 0; h < 10; ++h) {
        const short* ap = aggx + abase + h * 40;
        short8 a0 = *reinterpret_cast<const short8*>(ap);
        short8 a1 = *reinterpret_cast<const short8*>(ap + 32);  // k>=40 garbage x B-zero = 0
        f32x4 acc[3];
#pragma unroll
        for (int tt = 0; tt < 3; ++tt) acc[tt] = (f32x4){0.f, 0.f, 0.f, 0.f};
#pragma unroll
        for (int tt = 0; tt < 3; ++tt)
            acc[tt] = __builtin_amdgcn_mfma_f32_16x16x32_bf16(a0, W1g[((h * 2 + 0) * 3 + tt) * 64 + lane], acc[tt], 0, 0, 0);
#pragma unroll
        for (int tt = 0; tt < 3; ++tt)
            acc[tt] = __builtin_amdgcn_mfma_f32_16x16x32_bf16(a1, W1g[((h * 2 + 1) * 3 + tt) * 64 + lane], acc[tt], 0, 0, 0);
#pragma unroll
        for (int tt = 0; tt < 3; ++tt) {
            int c = tt * 16 + c_lo;
            if (c < C1) {
#pragma unroll
                for (int r = 0; r < 4; ++r) {
                    int node = m0 + grp * 4 + r;
                    float v = acc[tt][r];
                    v = (v > 0.f) ? v : expm1f(v);
                    x2p[(size_t)node * 352 + h * C1 + c] = bfbits(v);
                }
            }
        }
    }
    if (lane < 16) ((uint32*)x2p)[(size_t)(m0 + lane) * 176 + 175] = 0u;  // zero pad cols 350/351
}

// ---------------- layer 2 GEMM via MFMA, fused att dots ----------------
__global__ __launch_bounds__(256) void k_gemm2(const short* __restrict__ x2p,       // [N][352]
                                               const short8* __restrict__ W2f,
                                               const float* __restrict__ attS,
                                               const float* __restrict__ attD,
                                               unsigned short* __restrict__ h2b,    // [N][128]
                                               float* __restrict__ a_s2, float* __restrict__ a_d2) {
    const int lane = threadIdx.x & 63;
    const int wid = threadIdx.x >> 6;
    const int mtile = blockIdx.x * 4 + wid;
    if (mtile >= N_NODES / 16) return;
    const int c_lo = lane & 15, grp = lane >> 4;
    const int m0 = mtile * 16;
    const short* aptr = x2p + (size_t)(m0 + c_lo) * 352 + grp * 8;

    f32x4 acc[8];
#pragma unroll
    for (int t = 0; t < 8; ++t) acc[t] = (f32x4){0.f, 0.f, 0.f, 0.f};
#pragma unroll
    for (int kk = 0; kk < 11; ++kk) {
        short8 a = *reinterpret_cast<const short8*>(aptr + kk * 32);
#pragma unroll
        for (int t = 0; t < 8; ++t) {
            short8 b = W2f[(kk * 8 + t) * 64 + lane];
            acc[t] = __builtin_amdgcn_mfma_f32_16x16x32_bf16(a, b, acc[t], 0, 0, 0);
        }
    }
    float attSv[8], attDv[8];
#pragma unroll
    for (int t = 0; t < 8; ++t) {
        attSv[t] = attS[t * 16 + c_lo];
        attDv[t] = attD[t * 16 + c_lo];
    }
    float ps[4] = {0, 0, 0, 0}, pd[4] = {0, 0, 0, 0};
#pragma unroll
    for (int t = 0; t < 8; ++t)
#pragma unroll
        for (int r = 0; r < 4; ++r) {
            ps[r] = fmaf(acc[t][r], attSv[t], ps[r]);
            pd[r] = fmaf(acc[t][r], attDv[t], pd[r]);
        }
#pragma unroll
    for (int r = 0; r < 4; ++r) {
        int node = m0 + grp * 4 + r;
#pragma unroll
        for (int t = 0; t < 8; ++t) h2b[(size_t)node * C2 + t * 16 + c_lo] = bfbits(acc[t][r]);
    }
#pragma unroll
    for (int r = 0; r < 4; ++r) {
        float s = ps[r], dd = pd[r];
#pragma unroll
        for (int off = 1; off < 16; off <<= 1) {
            s += __shfl_xor(s, off);
            dd += __shfl_xor(dd, off);
        }
        if (c_lo == 0) {
            int node = m0 + grp * 4 + r;
            a_s2[node] = s;
            a_d2[node] = dd;
        }
    }
}

// ---------------- layer-2 aggregation -> out2 fp32 (bias+relu), no atomics ----------------
__global__ __launch_bounds__(256, 8) void k_agg2(const uint4* __restrict__ feat4,  // h2b [N][16]
                                                 const float* __restrict__ a_s,   // [N]
                                                 const float* __restrict__ a_d,
                                                 const int* __restrict__ offs,
                                                 const int* __restrict__ csr,
                                                 const float* __restrict__ b2,    // [128]
                                                 float* __restrict__ out2) {      // [N][128]
    const int lane = threadIdx.x & 63;
    const int wid = threadIdx.x >> 6;
    const int d = blockIdx.x * 4 + wid;
    const int o0 = offs[d];
    const int deg = offs[d + 1] - o0;
    const int total = deg + 1;
    const float add = a_d[d];
    const int g = lane >> 4, cl = lane & 15;

    float acc[8];
#pragma unroll
    for (int q = 0; q < 8; ++q) acc[q] = 0.f;
    float den = 0.f;

    for (int base = 0; base < total; base += 64) {
        const int i = base + lane;
        int s_mine = d;
        float e_mine = 0.f;
        if (i < total) {
            s_mine = (i < deg) ? csr[o0 + i] : d;
            e_mine = __expf(lrelu(a_s[s_mine] + add));
            den += e_mine;
        }
        const int cnt = min(64, total - base);
        int sj = __shfl(s_mine, g);
        float aj = __shfl(e_mine, g);
        uint4 vc = feat4[(size_t)sj * 16 + cl];
        for (int jb = 0; jb < cnt; jb += 4) {
            uint4 v = vc;
            float a = aj;
            if (jb + 4 < cnt) {
                int ni = jb + 4 + g;
                int sn = __shfl(s_mine, ni);
                aj = __shfl(e_mine, ni);
                vc = feat4[(size_t)sn * 16 + cl];
            }
            acc[0] = fmaf(a, bflo(v.x), acc[0]);
            acc[1] = fmaf(a, bfhi(v.x), acc[1]);
            acc[2] = fmaf(a, bflo(v.y), acc[2]);
            acc[3] = fmaf(a, bfhi(v.y), acc[3]);
            acc[4] = fmaf(a, bflo(v.z), acc[4]);
            acc[5] = fmaf(a, bfhi(v.z), acc[5]);
            acc[6] = fmaf(a, bflo(v.w), acc[6]);
            acc[7] = fmaf(a, bfhi(v.w), acc[7]);
        }
    }
#pragma unroll
    for (int q = 0; q < 8; ++q) {
        acc[q] += __shfl_xor(acc[q], 16);
        acc[q] += __shfl_xor(acc[q], 32);
    }
#pragma unroll
    for (int off = 32; off > 0; off >>= 1) den += __shfl_xor(den, off);

    if (lane < 16) {
        const float rden = 1.f / den;
        const float4* bp = (const float4*)(b2 + 8 * cl);
        float4 b0 = bp[0], b1 = bp[1];
        float4 o0v, o1v;
        o0v.x = fmaxf(acc[0] * rden + b0.x, 0.f);
        o0v.y = fmaxf(acc[1] * rden + b0.y, 0.f);
        o0v.z = fmaxf(acc[2] * rden + b0.z, 0.f);
        o0v.w = fmaxf(acc[3] * rden + b0.w, 0.f);
        o1v.x = fmaxf(acc[4] * rden + b1.x, 0.f);
        o1v.y = fmaxf(acc[5] * rden + b1.y, 0.f);
        o1v.z = fmaxf(acc[6] * rden + b1.z, 0.f);
        o1v.w = fmaxf(acc[7] * rden + b1.w, 0.f);
        float4* op = (float4*)(out2 + (size_t)d * C2 + 8 * cl);
        op[0] = o0v;
        op[1] = o1v;
    }
}

// ---------------- pooling: sorted-batch run-length max ----------------
__global__ __launch_bounds__(128) void k_pool(const float* __restrict__ out2,
                                              const int* __restrict__ batch,
                                              float* __restrict__ pooled) {
    const int c = threadIdx.x;
    const int n0 = blockIdx.x * 50;
    const int n1 = min(n0 + 50, N_NODES);
    int curB = batch[n0];
    float curM = 0.f;
    float v = out2[(size_t)n0 * C2 + c];
    for (int n = n0; n < n1; ++n) {
        float cur = v;
        int b = batch[n];
        if (n + 1 < n1) v = out2[(size_t)(n + 1) * C2 + c];
        if (b != curB) {
            atomicMax((int*)&pooled[curB * C2 + c], __float_as_int(curM));
            curB = b;
            curM = cur;
        } else {
            curM = fmaxf(curM, cur);
        }
    }
    atomicMax((int*)&pooled[curB * C2 + c], __float_as_int(curM));
}

// ---------------- dense head ----------------
__global__ __launch_bounds__(128) void k_head(const float* __restrict__ pooled,
                                              const float* __restrict__ Wg,
                                              const float* __restrict__ bg,
                                              const float* __restrict__ Wo,
                                              const float* __restrict__ bo,
                                              float* __restrict__ out) {
    __shared__ float p[C2];
    __shared__ float wsum[2];
    const int g = blockIdx.x;
    const int tid = threadIdx.x;
    p[tid] = pooled[g * C2 + tid];
    __syncthreads();
    float acc = bg[tid];
#pragma unroll 8
    for (int k = 0; k < C2; ++k) acc = fmaf(p[k], Wg[k * C2 + tid], acc);
    float z = fmaxf(acc, 0.f);
    float prod = z * Wo[tid];
#pragma unroll
    for (int off = 32; off; off >>= 1) prod += __shfl_down(prod, off);
    if ((tid & 63) == 0) wsum[tid >> 6] = prod;
    __syncthreads();
    if (tid == 0) out[g] = wsum[0] + wsum[1] + bo[0];
}

extern "C" void kernel_launch(void* const* d_in, const int* in_sizes, int n_in,
                              void* d_out, int out_size, void* d_ws, size_t ws_size,
                              hipStream_t stream) {
    const float* x        = (const float*)d_in[0];
    const int*   ei       = (const int*)d_in[1];
    const int*   batch    = (const int*)d_in[2];
    const float* W1       = (const float*)d_in[3];
    const float* att_src1 = (const float*)d_in[4];
    const float* att_dst1 = (const float*)d_in[5];
    const float* b1       = (const float*)d_in[6];
    const float* W2       = (const float*)d_in[7];
    const float* att_src2 = (const float*)d_in[8];
    const float* att_dst2 = (const float*)d_in[9];
    const float* b2       = (const float*)d_in[10];
    const float* Wg       = (const float*)d_in[11];
    const float* bg       = (const float*)d_in[12];
    const float* Wo       = (const float*)d_in[13];
    const float* bo       = (const float*)d_in[14];
    const int* src = ei;
    const int* dst = ei + N_EDGES;

    char* ws = (char*)d_ws;
    size_t off = 0;
    auto alloc = [&](size_t bytes) -> char* {
        char* p = ws + off;
        off = (off + bytes + 255) & ~(size_t)255;
        return p;
    };
    int*    deg    = (int*)alloc((size_t)N_NODES * 4);
    int*    offs   = (int*)alloc((size_t)(N_NODES + 1) * 4);
    int*    cursor = (int*)alloc((size_t)N_NODES * 4);
    int*    csr    = (int*)alloc((size_t)N_EDGES * 4);
    int*    bsum   = (int*)alloc((size_t)NB256 * 4);
    int*    bpre   = (int*)alloc((size_t)NB256 * 4);
    float*  a_s1   = (float*)alloc((size_t)N_NODES * H1 * 4);
    float*  a_d1   = (float*)alloc((size_t)N_NODES * H1 * 4);
    float*  a_s2   = (float*)alloc((size_t)N_NODES * 4);
    float*  a_d2   = (float*)alloc((size_t)N_NODES * 4);
    float*  pooled = (float*)alloc((size_t)N_GRAPHS * C2 * 4);
    float*  fold   = (float*)alloc((size_t)700 * 4);
    uint32* xbf    = (uint32*)alloc((size_t)N_NODES * 20 * 4);        // [N][40] bf16
    short*  aggx   = (short*)alloc((size_t)N_NODES * 400 * 2 + 256);  // [N*10][40] bf16 + slack
    uint32* x2p    = (uint32*)alloc((size_t)N_NODES * 176 * 4);       // [N][352] bf16
    unsigned short* h2b = (unsigned short*)alloc((size_t)N_NODES * C2 * 2);
    uint32* W1g    = (uint32*)alloc((size_t)10 * 2 * 3 * 64 * 16);
    uint32* W2f    = (uint32*)alloc((size_t)11 * 8 * 64 * 16);
    float*  out2   = (float*)aggx;  // aggx dead after k_gemm1b; 25.6 MB fits in 40 MB

    hipMemsetAsync(deg, 0, (size_t)N_NODES * 4, stream);
    hipMemsetAsync(pooled, 0, (size_t)N_GRAPHS * C2 * 4, stream);

    k_count<<<(N_EDGES + 255) / 256, 256, 0, stream>>>(dst, deg);
    k_bsum<<<NB256, 256, 0, stream>>>(deg, bsum);
    k_bscan<<<1, 256, 0, stream>>>(bsum, bpre);
    k_boffs<<<NB256, 256, 0, stream>>>(deg, bpre, offs, cursor);
    k_fill<<<(N_EDGES + 255) / 256, 256, 0, stream>>>(src, dst, cursor, csr);

    k_prep<<<XB + 3 + 15 + 22, 256, 0, stream>>>(x, W1, att_src1, att_dst1, b1, W2,
                                                 xbf, fold, W1g, W2f);
    k_att1<<<(N_NODES * 20 + 255) / 256, 256, 0, stream>>>(x, fold, a_s1, a_d1);

    k_aggx<<<N_NODES / 4, 256, 0, stream>>>((const uint4*)xbf, a_s1, a_d1, offs, csr,
                                            (uint4*)aggx);

    k_gemm1b<<<(N_NODES / 16 + 3) / 4, 256, 0, stream>>>(aggx, (const short8*)W1g,
                                                         (unsigned short*)x2p);

    k_gemm2<<<(N_NODES / 16 + 3) / 4, 256, 0, stream>>>((const short*)x2p, (const short8*)W2f,
                                                        att_src2, att_dst2, h2b, a_s2, a_d2);

    k_agg2<<<N_NODES / 4, 256, 0, stream>>>((const uint4*)h2b, a_s2, a_d2, offs, csr, b2, out2);

    k_pool<<<(N_NODES + 49) / 50, 128, 0, stream>>>(out2, batch, pooled);

    k_head<<<N_GRAPHS, 128, 0, stream>>>(pooled, Wg, bg, Wo, bo, (float*)d_out);
}